// Round 2
// baseline (1249.370 us; speedup 1.0000x reference)
//
#include <hip/hip_runtime.h>
#include <math.h>

// ---- problem constants ----
#define D    128
#define TT   128
#define E    100
#define NHD  2
#define BSZ  2048
#define N0C  6144
#define K0C  5
#define N1C  30720
#define K1C  10
#define NNC  200000
#define MC   4096
#define MSG  484
#define KIN  356        // D+E+T
#define HSTR 357        // per-head qw stride (356 cols + qb)
#define QWROW 714       // 2*HSTR

__device__ __forceinline__ float sigmoidf_(float x){ return 1.f/(1.f+__expf(-x)); }

// ---------- precompute: qc (time-const query bias), cb (fused out bias) ----------
__global__ void k_pre_small(const float* time_b,
                            const float* Wq0,const float* bq0,const float* Wq1,const float* bq1,
                            const float* bv0,const float* Wo0,const float* bo0,
                            const float* bv1,const float* Wo1,const float* bo1,
                            float* qc0, float* qc1, float* cb0, float* cb1){
    __shared__ float cosb[TT];
    int j = threadIdx.x; // 128 threads
    cosb[j] = cosf(time_b[j]);
    __syncthreads();
    float a0=bq0[j], a1=bq1[j];
    for(int t=0;t<TT;++t){ a0 += cosb[t]*Wq0[(D+t)*D + j]; a1 += cosb[t]*Wq1[(D+t)*D + j]; }
    qc0[j]=a0; qc1[j]=a1;
    float c0=bo0[j], c1=bo1[j];
    for(int jp=0;jp<D;++jp){ c0 += bv0[jp]*Wo0[jp*D + j]; c1 += bv1[jp]*Wo1[jp*D + j]; }
    cb0[j]=c0; cb1[j]=c1;
}

// WF[k][h*357+c] = sum_d Wq[k][h*64+d] * (c<356 ? Wk[c][h*64+d] : bk[h*64+d])
// cF[col] = sum_d qc[h*64+d] * same
__global__ void k_wf(const float* Wq0,const float* Wk0,const float* bk0,const float* qc0,
                     const float* Wq1,const float* Wk1,const float* bk1,const float* qc1,
                     float* WF0, float* cF0, float* WF1, float* cF1){
    int l = blockIdx.x / QWROW; int col = blockIdx.x % QWROW;
    int h = col / HSTR; int c = col % HSTR;
    const float* Wq = l? Wq1:Wq0; const float* Wk = l? Wk1:Wk0;
    const float* bk = l? bk1:bk0; const float* qc = l? qc1:qc0;
    float* WF = l? WF1:WF0; float* cF = l? cF1:cF0;
    int k = threadIdx.x;
    float a = 0.f;
    for(int d=0; d<64; ++d){
        float wkv = (c < KIN) ? Wk[c*D + h*64+d] : bk[h*64+d];
        a += Wq[k*D + h*64+d] * wkv;
    }
    WF[(size_t)k*QWROW + col] = a;
    if(k==0){
        float s=0.f;
        for(int d=0; d<64; ++d){
            float wkv = (c < KIN) ? Wk[c*D + h*64+d] : bk[h*64+d];
            s += qc[h*64+d]*wkv;
        }
        cF[col] = s;
    }
}

// packed Wvo: rows r = h*(356-cmin) + (c-cmin); Wvo[r][j] = sum_d Wv[c][h*64+d]*Wo[(h*64+d)][j]
__global__ void k_wvo(const float* Wv,const float* Wo, float* Wvo, int cmin){
    int span = KIN - cmin;
    int r = blockIdx.x;
    int h = r / span; int c = cmin + (r - h*span);
    int j = threadIdx.x;
    float a = 0.f;
    for(int d=0; d<64; ++d) a += Wv[c*D + h*64+d] * Wo[(h*64+d)*D + j];
    Wvo[(size_t)r*D + j] = a;
}

// ---------- GRU memory update on M rows ----------
__global__ void k_map_init(int* map){ int i = blockIdx.x*256+threadIdx.x; if(i<NNC) map[i] = -1; }
__global__ void k_map_scatter(const int* msg_nids, int* map){
    int i = blockIdx.x*256+threadIdx.x; if(i<MC) map[msg_nids[i]] = i;
}

// 8 msgs/block, 384 threads (gate g = tid>>7 in parallel), two-phase
__global__ __launch_bounds__(384) void k_gru(const float* msgs, const float* memory, const int* msg_nids,
                      const float* Wih, const float* bih, const float* Whh, const float* bhh,
                      float* upd){
    __shared__ float xs[8*MSG];
    __shared__ float hsm[8*D];
    __shared__ float si[3*128*8];
    __shared__ float sh[3*128*8];
    int blk = blockIdx.x; int tid = threadIdx.x;
    const float* mrow = msgs + (size_t)blk*8*MSG;
    for(int i=tid; i<8*MSG; i+=384) xs[i] = mrow[i];
    for(int i=tid; i<8*D; i+=384){
        int m = i>>7; int c = i&127;
        hsm[i] = memory[(size_t)msg_nids[blk*8+m]*D + c];
    }
    __syncthreads();
    int g = tid>>7, d = tid&127;
    float ai[8], ah[8];
    #pragma unroll
    for(int m=0;m<8;++m){ ai[m]=0.f; ah[m]=0.f; }
    const float* wi = Wih + (size_t)(g*D+d)*MSG;
    for(int c=0;c<MSG;c+=4){
        float4 w4 = *(const float4*)(wi + c);
        #pragma unroll
        for(int m=0;m<8;++m){
            float4 x4 = *(const float4*)(xs + m*MSG + c);
            ai[m] += w4.x*x4.x + w4.y*x4.y + w4.z*x4.z + w4.w*x4.w;
        }
    }
    const float* wh = Whh + (size_t)(g*D+d)*D;
    for(int c=0;c<D;c+=4){
        float4 w4 = *(const float4*)(wh + c);
        #pragma unroll
        for(int m=0;m<8;++m){
            float4 h4 = *(const float4*)(hsm + m*D + c);
            ah[m] += w4.x*h4.x + w4.y*h4.y + w4.z*h4.z + w4.w*h4.w;
        }
    }
    float bi = bih[g*D+d], bh = bhh[g*D+d];
    #pragma unroll
    for(int m=0;m<8;++m){ si[tid*8+m] = ai[m]+bi; sh[tid*8+m] = ah[m]+bh; }
    __syncthreads();
    if(tid < 128){
        #pragma unroll
        for(int m=0;m<8;++m){
            float ir = si[(0*128+tid)*8+m], hr = sh[(0*128+tid)*8+m];
            float iz = si[(1*128+tid)*8+m], hz = sh[(1*128+tid)*8+m];
            float in_= si[(2*128+tid)*8+m], hn = sh[(2*128+tid)*8+m];
            float r = sigmoidf_(ir+hr);
            float u = sigmoidf_(iz+hz);
            float nn = tanhf(in_ + r*hn);
            upd[(size_t)(blk*8+m)*D + tid] = (1.f-u)*nn + u*hsm[m*D+tid];
        }
    }
}

// gather node memories through the update map
__global__ void k_gather(const int* seed, const int* map, const float* memory, const float* upd,
                         float* hout, int nelem){
    int i = blockIdx.x*256 + threadIdx.x;
    if(i >= nelem) return;
    int row = i>>7, c = i&127;
    int sid = seed[row];
    int mi = map[sid];
    hout[i] = (mi>=0) ? upd[(size_t)mi*D + c] : memory[(size_t)sid*D + c];
}

// ---------- GEMM1: qw[M x 714] = h[M x 128] @ WF[128 x 714] + cF ----------
// BM=128 BN=128 BK=32, 256 threads, 8x8 microtile
__global__ __launch_bounds__(256) void k_gemm1(const float* A, const float* WF, const float* cF,
                                               float* C){
    __shared__ float As[32*132];
    __shared__ float Bs[32*132];
    int t = threadIdx.x;
    int n0 = blockIdx.x * 128;
    int bm0 = blockIdx.y * 128;
    int ty = t >> 4, tx = t & 15;
    float acc[8][8];
    #pragma unroll
    for(int i=0;i<8;++i)
        #pragma unroll
        for(int j=0;j<8;++j) acc[i][j]=0.f;

    for(int kt=0; kt<4; ++kt){
        int k0 = kt*32;
        // stage A (transposed): tile 128 rows x 32 k = 1024 float4
        #pragma unroll
        for(int jj=0; jj<4; ++jj){
            int f = t + jj*256;
            int row = f >> 3; int kc4 = f & 7;
            float4 a4 = *(const float4*)(A + (size_t)(bm0+row)*D + k0 + kc4*4);
            As[(kc4*4+0)*132 + row] = a4.x;
            As[(kc4*4+1)*132 + row] = a4.y;
            As[(kc4*4+2)*132 + row] = a4.z;
            As[(kc4*4+3)*132 + row] = a4.w;
        }
        // stage B: 32 rows x 128 cols, col-guarded
        #pragma unroll
        for(int jj=0; jj<16; ++jj){
            int f = t + jj*256;
            int row = f >> 7; int col = f & 127;
            int n = n0 + col;
            Bs[row*132 + col] = (n < QWROW) ? WF[(size_t)(k0+row)*QWROW + n] : 0.f;
        }
        __syncthreads();
        for(int k=0;k<32;++k){
            float4 a0 = *(const float4*)(As + k*132 + ty*8);
            float4 a1 = *(const float4*)(As + k*132 + ty*8 + 4);
            float4 b0 = *(const float4*)(Bs + k*132 + tx*8);
            float4 b1 = *(const float4*)(Bs + k*132 + tx*8 + 4);
            float av[8] = {a0.x,a0.y,a0.z,a0.w,a1.x,a1.y,a1.z,a1.w};
            float bv[8] = {b0.x,b0.y,b0.z,b0.w,b1.x,b1.y,b1.z,b1.w};
            #pragma unroll
            for(int i=0;i<8;++i)
                #pragma unroll
                for(int j=0;j<8;++j) acc[i][j] += av[i]*bv[j];
        }
        __syncthreads();
    }
    #pragma unroll
    for(int i=0;i<8;++i){
        int m = bm0 + ty*8 + i;
        #pragma unroll
        for(int j=0;j<8;++j){
            int n = n0 + tx*8 + j;
            if(n < QWROW) C[(size_t)m*QWROW + n] = acc[i][j] + cF[n];
        }
    }
}

// ---------- GEMM2: z[M x 128] = relu(A1[M x K1 (lda 714)]@W1 + h[M x 128]@W2 + cb) ----------
// BM=64 BN=128 BK=32, 256 threads, 4x8 microtile
__global__ __launch_bounds__(256) void k_gemm2(const float* A1, int K1, const float* A2,
                                               const float* W1, const float* W2,
                                               const float* cb, float* Cz){
    __shared__ float As[32*68];
    __shared__ float Bs[32*132];
    int t = threadIdx.x;
    int bm0 = blockIdx.x * 64;
    int ty = t >> 4, tx = t & 15;
    int Ktot = K1 + D;
    int ntiles = (Ktot + 31) >> 5;
    float acc[4][8];
    #pragma unroll
    for(int i=0;i<4;++i)
        #pragma unroll
        for(int j=0;j<8;++j) acc[i][j]=0.f;

    for(int kt=0; kt<ntiles; ++kt){
        int k0 = kt*32;
        // stage A: 64 rows x 32 k, source-select, scalar
        #pragma unroll
        for(int jj=0; jj<8; ++jj){
            int f = t + jj*256;
            int row = f >> 5; int kl = f & 31;
            int kg = k0 + kl;
            int rg = bm0 + row;
            float v = 0.f;
            if(kg < K1)        v = A1[(size_t)rg*QWROW + kg];
            else if(kg < Ktot) v = A2[(size_t)rg*D + (kg-K1)];
            As[kl*68 + row] = v;
        }
        // stage B: 32 k-rows x 128 cols, source-select
        #pragma unroll
        for(int jj=0; jj<16; ++jj){
            int f = t + jj*256;
            int row = f >> 7; int col = f & 127;
            int kg = k0 + row;
            float v = 0.f;
            if(kg < K1)        v = W1[(size_t)kg*D + col];
            else if(kg < Ktot) v = W2[(size_t)(kg-K1)*D + col];
            Bs[row*132 + col] = v;
        }
        __syncthreads();
        for(int k=0;k<32;++k){
            float4 a0 = *(const float4*)(As + k*68 + ty*4);
            float4 b0 = *(const float4*)(Bs + k*132 + tx*8);
            float4 b1 = *(const float4*)(Bs + k*132 + tx*8 + 4);
            float av[4] = {a0.x,a0.y,a0.z,a0.w};
            float bv[8] = {b0.x,b0.y,b0.z,b0.w,b1.x,b1.y,b1.z,b1.w};
            #pragma unroll
            for(int i=0;i<4;++i)
                #pragma unroll
                for(int j=0;j<8;++j) acc[i][j] += av[i]*bv[j];
        }
        __syncthreads();
    }
    #pragma unroll
    for(int i=0;i<4;++i){
        int m = bm0 + ty*4 + i;
        #pragma unroll
        for(int j=0;j<8;++j){
            int n = tx*8 + j;
            Cz[(size_t)m*D + n] = fmaxf(acc[i][j] + cb[n], 0.f);
        }
    }
}

// fused scores + masked softmax + av; one wave per node; packed av written into qw row
template<int K, int CMIN, int S>
__global__ __launch_bounds__(64) void k_attn(float* qwav,
    const float* times, const float* nbr_times, const float* nbr_feats,
    const int* nbr_mask, const int* nbr_local, const float* zbuf,
    const float* time_w, const float* time_b){
    int n = blockIdx.x; int lane = threadIdx.x;
    float qwreg[NHD][S], qb[NHD];
    #pragma unroll
    for(int h=0;h<NHD;++h){
        qb[h] = qwav[(size_t)n*QWROW + h*HSTR + KIN];
        #pragma unroll
        for(int s=0;s<S;++s){
            int c = CMIN + s*64 + lane;
            qwreg[h][s] = (c < KIN) ? qwav[(size_t)n*QWROW + h*HSTR + c] : 0.f;
        }
    }
    float tw[S], tb[S];
    #pragma unroll
    for(int s=0;s<S;++s){
        int c = CMIN + s*64 + lane;
        if(c >= D+E && c < KIN){ tw[s]=time_w[c-(D+E)]; tb[s]=time_b[c-(D+E)]; }
        else { tw[s]=0.f; tb[s]=0.f; }
    }
    float tn = times[n];
    float kinreg[K][S];
    float sval[NHD][K];
    #pragma unroll
    for(int k=0;k<K;++k){
        float dt = tn - nbr_times[(size_t)n*K + k];
        const float* ef = nbr_feats + (size_t)(n*K+k)*E;
        const float* zf = (CMIN==0) ? (zbuf + (size_t)(nbr_local[(size_t)n*K+k] - N0C)*D) : (const float*)0;
        float p0=0.f, p1=0.f;
        #pragma unroll
        for(int s=0;s<S;++s){
            int c = CMIN + s*64 + lane;
            float kv = 0.f;
            if(c < KIN){
                if(CMIN==0 && c < D)      kv = zf[c];
                else if(c < D+E)          kv = ef[c-D];
                else                      kv = __cosf(dt*tw[s] + tb[s]);
            }
            kinreg[k][s] = kv;
            p0 += kv * qwreg[0][s];
            p1 += kv * qwreg[1][s];
        }
        #pragma unroll
        for(int off=32; off; off>>=1){ p0 += __shfl_xor(p0, off); p1 += __shfl_xor(p1, off); }
        int mk = nbr_mask[(size_t)n*K + k];
        sval[0][k] = (mk>0) ? (p0 + qb[0])*0.125f : -1e9f;
        sval[1][k] = (mk>0) ? (p1 + qb[1])*0.125f : -1e9f;
    }
    float a[NHD][K];
    #pragma unroll
    for(int h=0;h<NHD;++h){
        float mx = -1e30f;
        #pragma unroll
        for(int k=0;k<K;++k) mx = fmaxf(mx, sval[h][k]);
        float z=0.f;
        #pragma unroll
        for(int k=0;k<K;++k){ float e = __expf(sval[h][k]-mx); a[h][k]=e; z+=e; }
        float inv = 1.f/z;
        #pragma unroll
        for(int k=0;k<K;++k) a[h][k]*=inv;
    }
    // write packed av into the same qw row: col h*(KIN-CMIN) + (c-CMIN)
    #pragma unroll
    for(int h=0;h<NHD;++h)
      #pragma unroll
      for(int s=0;s<S;++s){
        int c = CMIN + s*64 + lane;
        if(c < KIN){
            float v=0.f;
            #pragma unroll
            for(int k=0;k<K;++k) v += a[h][k]*kinreg[k][s];
            qwav[(size_t)n*QWROW + h*(KIN-CMIN) + (c-CMIN)] = v;
        }
      }
}

// link prediction: both (src,dst) and (src,neg) per block
__global__ __launch_bounds__(128) void k_linkpred(const float* z0,
      const int* src,const int* dst,const int* neg,
      const float* Ws,const float* bs,const float* Wd,const float* bd,
      const float* Wo,const float* bo, float* out){
    __shared__ float zs[D], zd[D], zn[D];
    __shared__ float red[4];
    int b = blockIdx.x; int d = threadIdx.x;
    zs[d] = z0[(size_t)src[b]*D + d];
    zd[d] = z0[(size_t)dst[b]*D + d];
    zn[d] = z0[(size_t)neg[b]*D + d];
    __syncthreads();
    float ss=0.f, sdd=0.f, snn=0.f;
    for(int c=0;c<D;++c){
        float w1 = Ws[c*D + d], w2 = Wd[c*D + d];
        ss  += zs[c]*w1; sdd += zd[c]*w2; snn += zn[c]*w2;
    }
    float bb = bs[d] + bd[d];
    float h1 = fmaxf(ss + sdd + bb, 0.f);
    float h2 = fmaxf(ss + snn + bb, 0.f);
    float w = Wo[d];
    float v1 = h1*w, v2 = h2*w;
    #pragma unroll
    for(int off=32; off; off>>=1){ v1 += __shfl_xor(v1,off); v2 += __shfl_xor(v2,off); }
    int wid = d>>6;
    if((d&63)==0){ red[wid*2]=v1; red[wid*2+1]=v2; }
    __syncthreads();
    if(d==0){
        out[b]       = sigmoidf_(red[0]+red[2] + bo[0]);
        out[BSZ + b] = sigmoidf_(red[1]+red[3] + bo[0]);
    }
}

extern "C" void kernel_launch(void* const* d_in, const int* in_sizes, int n_in,
                              void* d_out, int out_size, void* d_ws, size_t ws_size,
                              hipStream_t stream) {
    const float* memory  = (const float*)d_in[0];
    const float* time_w  = (const float*)d_in[1];
    const float* time_b  = (const float*)d_in[2];
    const float* gWih    = (const float*)d_in[3];
    const float* gbih    = (const float*)d_in[4];
    const float* gWhh    = (const float*)d_in[5];
    const float* gbhh    = (const float*)d_in[6];
    const float* Wq0=(const float*)d_in[7],  *bq0=(const float*)d_in[8];
    const float* Wk0=(const float*)d_in[9],  *bk0=(const float*)d_in[10];
    const float* Wv0=(const float*)d_in[11], *bv0=(const float*)d_in[12];
    const float* Wo0=(const float*)d_in[13], *bo0=(const float*)d_in[14];
    const float* Wq1=(const float*)d_in[15], *bq1=(const float*)d_in[16];
    const float* Wk1=(const float*)d_in[17], *bk1=(const float*)d_in[18];
    const float* Wv1=(const float*)d_in[19], *bv1=(const float*)d_in[20];
    const float* Wo1=(const float*)d_in[21], *bo1=(const float*)d_in[22];
    const float* lpWs=(const float*)d_in[23], *lpbs=(const float*)d_in[24];
    const float* lpWd=(const float*)d_in[25], *lpbd=(const float*)d_in[26];
    const float* lpWo=(const float*)d_in[27], *lpbo=(const float*)d_in[28];
    const float* msgs    = (const float*)d_in[29];
    const float* times0  = (const float*)d_in[30];
    const float* ntimes0 = (const float*)d_in[31];
    const float* nfeats0 = (const float*)d_in[32];
    const float* times1  = (const float*)d_in[33];
    const float* ntimes1 = (const float*)d_in[34];
    const float* nfeats1 = (const float*)d_in[35];
    const int* msg_nids  = (const int*)d_in[36];
    const int* seed0     = (const int*)d_in[37];
    const int* seed1     = (const int*)d_in[38];
    const int* nbr_local0= (const int*)d_in[39];
    const int* nbr_mask0 = (const int*)d_in[40];
    const int* nbr_mask1 = (const int*)d_in[41];
    const int* src       = (const int*)d_in[42];
    const int* dst       = (const int*)d_in[43];
    const int* neg       = (const int*)d_in[44];

    char* ws = (char*)d_ws;
    size_t off = 0;
    auto alloc = [&](size_t bytes)->char*{
        char* p = ws + off;
        off += (bytes + 255) & ~(size_t)255;
        return p;
    };
    int*   map  = (int*)  alloc((size_t)NNC*4);
    float* upd  = (float*)alloc((size_t)MC*D*4);
    float* h1   = (float*)alloc((size_t)N1C*D*4);
    float* qw1  = (float*)alloc((size_t)N1C*QWROW*4);   // also holds packed av1 after attn
    float* z1   = (float*)alloc((size_t)N1C*D*4);
    float* h0   = (float*)alloc((size_t)N0C*D*4);
    float* qw0  = (float*)alloc((size_t)N0C*QWROW*4);   // also holds packed av0
    float* z0   = (float*)alloc((size_t)N0C*D*4);
    float* qc0  = (float*)alloc(512);
    float* qc1  = (float*)alloc(512);
    float* cb0  = (float*)alloc(512);
    float* cb1  = (float*)alloc(512);
    float* WF0  = (float*)alloc((size_t)D*QWROW*4);
    float* WF1  = (float*)alloc((size_t)D*QWROW*4);
    float* cF0  = (float*)alloc((size_t)QWROW*4);
    float* cF1  = (float*)alloc((size_t)QWROW*4);
    float* Wvo0 = (float*)alloc((size_t)2*KIN*D*4);          // 712 rows
    float* Wvo1 = (float*)alloc((size_t)2*(KIN-128)*D*4);    // 456 rows
    float* outp = (float*)d_out;

    // precompute
    k_pre_small<<<1,128,0,stream>>>(time_b, Wq0,bq0,Wq1,bq1, bv0,Wo0,bo0, bv1,Wo1,bo1,
                                    qc0,qc1,cb0,cb1);
    k_wf<<<2*QWROW,128,0,stream>>>(Wq0,Wk0,bk0,qc0, Wq1,Wk1,bk1,qc1, WF0,cF0,WF1,cF1);
    k_wvo<<<2*KIN,128,0,stream>>>(Wv0,Wo0,Wvo0,0);
    k_wvo<<<2*(KIN-128),128,0,stream>>>(Wv1,Wo1,Wvo1,128);

    // GRU memory update
    k_map_init<<<(NNC+255)/256,256,0,stream>>>(map);
    k_map_scatter<<<MC/256,256,0,stream>>>(msg_nids, map);
    k_gru<<<MC/8,384,0,stream>>>(msgs, memory, msg_nids, gWih,gbih,gWhh,gbhh, upd);

    // gather node states
    k_gather<<<(N1C*D)/256,256,0,stream>>>(seed1, map, memory, upd, h1, N1C*D);
    k_gather<<<(N0C*D)/256,256,0,stream>>>(seed0, map, memory, upd, h0, N0C*D);

    // hop 1
    {
        dim3 g1((QWROW+127)/128, N1C/128);
        k_gemm1<<<g1,256,0,stream>>>(h1, WF1, cF1, qw1);
        k_attn<K1C,128,4><<<N1C,64,0,stream>>>(qw1, times1, ntimes1, nfeats1,
                                               nbr_mask1, (const int*)0, (const float*)0,
                                               time_w, time_b);
        k_gemm2<<<N1C/64,256,0,stream>>>(qw1, 2*(KIN-128), h1, Wvo1, Wo1 + D*D, cb1, z1);
    }
    // hop 0
    {
        dim3 g0((QWROW+127)/128, N0C/128);
        k_gemm1<<<g0,256,0,stream>>>(h0, WF0, cF0, qw0);
        k_attn<K0C,0,6><<<N0C,64,0,stream>>>(qw0, times0, ntimes0, nfeats0,
                                             nbr_mask0, nbr_local0, z1,
                                             time_w, time_b);
        k_gemm2<<<N0C/64,256,0,stream>>>(qw0, 2*KIN, h0, Wvo0, Wo0 + D*D, cb0, z0);
    }

    // link prediction
    k_linkpred<<<BSZ,128,0,stream>>>(z0, src,dst,neg, lpWs,lpbs,lpWd,lpbd, lpWo,lpbo, outp);
}

// Round 3
// 896.535 us; speedup vs baseline: 1.3936x; 1.3936x over previous
//
#include <hip/hip_runtime.h>
#include <math.h>

// ---- problem constants ----
#define D    128
#define TT   128
#define E    100
#define NHD  2
#define BSZ  2048
#define N0C  6144
#define K0C  5
#define N1C  30720
#define K1C  10
#define NNC  200000
#define MC   4096
#define MSG  484
#define KIN  356        // D+E+T
#define HSTR 357        // per-head qw stride (356 cols + qb)
#define QWROW 714       // 2*HSTR

__device__ __forceinline__ float sigmoidf_(float x){ return 1.f/(1.f+__expf(-x)); }

// ---------- precompute: qc (time-const query bias), cb (fused out bias) ----------
__global__ void k_pre_small(const float* time_b,
                            const float* Wq0,const float* bq0,const float* Wq1,const float* bq1,
                            const float* bv0,const float* Wo0,const float* bo0,
                            const float* bv1,const float* Wo1,const float* bo1,
                            float* qc0, float* qc1, float* cb0, float* cb1){
    __shared__ float cosb[TT];
    int j = threadIdx.x; // 128 threads
    cosb[j] = cosf(time_b[j]);
    __syncthreads();
    float a0=bq0[j], a1=bq1[j];
    for(int t=0;t<TT;++t){ a0 += cosb[t]*Wq0[(D+t)*D + j]; a1 += cosb[t]*Wq1[(D+t)*D + j]; }
    qc0[j]=a0; qc1[j]=a1;
    float c0=bo0[j], c1=bo1[j];
    for(int jp=0;jp<D;++jp){ c0 += bv0[jp]*Wo0[jp*D + j]; c1 += bv1[jp]*Wo1[jp*D + j]; }
    cb0[j]=c0; cb1[j]=c1;
}

// WF[k][h*357+c] = sum_d Wq[k][h*64+d] * (c<356 ? Wk[c][h*64+d] : bk[h*64+d])
__global__ void k_wf(const float* Wq0,const float* Wk0,const float* bk0,const float* qc0,
                     const float* Wq1,const float* Wk1,const float* bk1,const float* qc1,
                     float* WF0, float* cF0, float* WF1, float* cF1){
    int l = blockIdx.x / QWROW; int col = blockIdx.x % QWROW;
    int h = col / HSTR; int c = col % HSTR;
    const float* Wq = l? Wq1:Wq0; const float* Wk = l? Wk1:Wk0;
    const float* bk = l? bk1:bk0; const float* qc = l? qc1:qc0;
    float* WF = l? WF1:WF0; float* cF = l? cF1:cF0;
    int k = threadIdx.x;
    float a = 0.f;
    for(int d=0; d<64; ++d){
        float wkv = (c < KIN) ? Wk[c*D + h*64+d] : bk[h*64+d];
        a += Wq[k*D + h*64+d] * wkv;
    }
    WF[(size_t)k*QWROW + col] = a;
    if(k==0){
        float s=0.f;
        for(int d=0; d<64; ++d){
            float wkv = (c < KIN) ? Wk[c*D + h*64+d] : bk[h*64+d];
            s += qc[h*64+d]*wkv;
        }
        cF[col] = s;
    }
}

// packed Wvo: rows r = h*(356-cmin) + (c-cmin); Wvo[r][j] = sum_d Wv[c][h*64+d]*Wo[(h*64+d)][j]
__global__ void k_wvo(const float* Wv,const float* Wo, float* Wvo, int cmin){
    int span = KIN - cmin;
    int r = blockIdx.x;
    int h = r / span; int c = cmin + (r - h*span);
    int j = threadIdx.x;
    float a = 0.f;
    for(int d=0; d<64; ++d) a += Wv[c*D + h*64+d] * Wo[(h*64+d)*D + j];
    Wvo[(size_t)r*D + j] = a;
}

// ---------- GRU memory update on M rows ----------
__global__ void k_map_init(int* map){ int i = blockIdx.x*256+threadIdx.x; if(i<NNC) map[i] = -1; }
__global__ void k_map_scatter(const int* msg_nids, int* map){
    int i = blockIdx.x*256+threadIdx.x; if(i<MC) map[msg_nids[i]] = i;
}

// 8 msgs/block, 384 threads (gate g = tid>>7 in parallel), two-phase
__global__ __launch_bounds__(384) void k_gru(const float* msgs, const float* memory, const int* msg_nids,
                      const float* Wih, const float* bih, const float* Whh, const float* bhh,
                      float* upd){
    __shared__ float xs[8*MSG];
    __shared__ float hsm[8*D];
    __shared__ float si[3*128*8];
    __shared__ float sh[3*128*8];
    int blk = blockIdx.x; int tid = threadIdx.x;
    const float* mrow = msgs + (size_t)blk*8*MSG;
    for(int i=tid; i<8*MSG; i+=384) xs[i] = mrow[i];
    for(int i=tid; i<8*D; i+=384){
        int m = i>>7; int c = i&127;
        hsm[i] = memory[(size_t)msg_nids[blk*8+m]*D + c];
    }
    __syncthreads();
    int g = tid>>7, d = tid&127;
    float ai[8], ah[8];
    #pragma unroll
    for(int m=0;m<8;++m){ ai[m]=0.f; ah[m]=0.f; }
    const float* wi = Wih + (size_t)(g*D+d)*MSG;
    for(int c=0;c<MSG;c+=4){
        float4 w4 = *(const float4*)(wi + c);
        #pragma unroll
        for(int m=0;m<8;++m){
            float4 x4 = *(const float4*)(xs + m*MSG + c);
            ai[m] += w4.x*x4.x + w4.y*x4.y + w4.z*x4.z + w4.w*x4.w;
        }
    }
    const float* wh = Whh + (size_t)(g*D+d)*D;
    for(int c=0;c<D;c+=4){
        float4 w4 = *(const float4*)(wh + c);
        #pragma unroll
        for(int m=0;m<8;++m){
            float4 h4 = *(const float4*)(hsm + m*D + c);
            ah[m] += w4.x*h4.x + w4.y*h4.y + w4.z*h4.z + w4.w*h4.w;
        }
    }
    float bi = bih[g*D+d], bh = bhh[g*D+d];
    #pragma unroll
    for(int m=0;m<8;++m){ si[tid*8+m] = ai[m]+bi; sh[tid*8+m] = ah[m]+bh; }
    __syncthreads();
    if(tid < 128){
        #pragma unroll
        for(int m=0;m<8;++m){
            float ir = si[(0*128+tid)*8+m], hr = sh[(0*128+tid)*8+m];
            float iz = si[(1*128+tid)*8+m], hz = sh[(1*128+tid)*8+m];
            float in_= si[(2*128+tid)*8+m], hn = sh[(2*128+tid)*8+m];
            float r = sigmoidf_(ir+hr);
            float u = sigmoidf_(iz+hz);
            float nn = tanhf(in_ + r*hn);
            upd[(size_t)(blk*8+m)*D + tid] = (1.f-u)*nn + u*hsm[m*D+tid];
        }
    }
}

// fused gather for both hops
__global__ void k_gatherf(const int* seed1,const int* seed0,const int* map,
                          const float* memory,const float* upd,float* h1,float* h0){
    int i = blockIdx.x*256 + threadIdx.x;
    const int total1 = N1C*D;
    const int* seed; float* dst; int li;
    if(i < total1){ seed=seed1; dst=h1; li=i; }
    else { li = i - total1; if(li >= N0C*D) return; seed=seed0; dst=h0; }
    int row = li>>7, c = li&127;
    int sid = seed[row];
    int mi = map[sid];
    dst[li] = (mi>=0) ? upd[(size_t)mi*D + c] : memory[(size_t)sid*D + c];
}

// ---------- fused GEMM1 (both hops): qw[M x 714] = h[M x 128] @ WF + cF ----------
// BM=128 BN=128 BK=32, 256 threads, 8x8 microtile, double-buffered
__global__ __launch_bounds__(256) void k_gemm1f(const float* h1, const float* WF1, const float* cF1, float* C1,
                                                const float* h0, const float* WF0, const float* cF0, float* C0){
    __shared__ float As[2][32*132];
    __shared__ float Bs[2][32*132];
    const int NB1 = N1C/128;       // 240
    int by = blockIdx.y;
    const float* A; const float* B; const float* cF; float* C; int bm0;
    if(by < NB1){ A=h1; B=WF1; cF=cF1; C=C1; bm0=by*128; }
    else        { A=h0; B=WF0; cF=cF0; C=C0; bm0=(by-NB1)*128; }
    int n0 = blockIdx.x * 128;
    int t = threadIdx.x;
    int tx = t & 15, ty = t >> 4;

    float acc[8][8];
    #pragma unroll
    for(int i=0;i<8;++i)
        #pragma unroll
        for(int j=0;j<8;++j) acc[i][j]=0.f;

    float4 apre[4]; float bpre[16];
    auto loadA = [&](int kt){
        int k0 = kt*32;
        #pragma unroll
        for(int i=0;i<4;++i){
            int idx = t + i*256;          // [0,1024)
            int row = idx >> 3; int k4 = idx & 7;
            apre[i] = *(const float4*)(A + (size_t)(bm0+row)*D + k0 + k4*4);
        }
    };
    auto loadB = [&](int kt){
        int k0 = kt*32;
        #pragma unroll
        for(int i=0;i<16;++i){
            int idx = t + i*256;          // [0,4096)
            int kr = idx >> 7; int col = idx & 127;
            int n = n0 + col;
            bpre[i] = (n < QWROW) ? B[(size_t)(k0+kr)*QWROW + n] : 0.f;
        }
    };
    auto stash = [&](int buf){
        #pragma unroll
        for(int i=0;i<4;++i){
            int idx = t + i*256;
            int row = idx >> 3; int k4 = idx & 7;
            As[buf][(k4*4+0)*132 + row] = apre[i].x;
            As[buf][(k4*4+1)*132 + row] = apre[i].y;
            As[buf][(k4*4+2)*132 + row] = apre[i].z;
            As[buf][(k4*4+3)*132 + row] = apre[i].w;
        }
        #pragma unroll
        for(int i=0;i<16;++i){
            int idx = t + i*256;
            int kr = idx >> 7; int col = idx & 127;
            Bs[buf][kr*132 + col] = bpre[i];
        }
    };

    loadA(0); loadB(0); stash(0); __syncthreads();
    for(int kt=0; kt<4; ++kt){
        int cur = kt & 1;
        if(kt < 3){ loadA(kt+1); loadB(kt+1); }
        for(int k=0;k<32;++k){
            float4 a0 = *(const float4*)(&As[cur][k*132 + ty*8]);
            float4 a1 = *(const float4*)(&As[cur][k*132 + ty*8 + 4]);
            float4 b0 = *(const float4*)(&Bs[cur][k*132 + tx*8]);
            float4 b1 = *(const float4*)(&Bs[cur][k*132 + tx*8 + 4]);
            float av[8] = {a0.x,a0.y,a0.z,a0.w,a1.x,a1.y,a1.z,a1.w};
            float bv[8] = {b0.x,b0.y,b0.z,b0.w,b1.x,b1.y,b1.z,b1.w};
            #pragma unroll
            for(int i=0;i<8;++i)
                #pragma unroll
                for(int j=0;j<8;++j) acc[i][j] += av[i]*bv[j];
        }
        if(kt < 3){ stash(cur^1); __syncthreads(); }
    }
    #pragma unroll
    for(int i=0;i<8;++i){
        int m = bm0 + ty*8 + i;
        #pragma unroll
        for(int j=0;j<8;++j){
            int n = n0 + tx*8 + j;
            if(n < QWROW) C[(size_t)m*QWROW + n] = acc[i][j] + cF[n];
        }
    }
}

// ---------- GEMM2: z[M x 128] = relu(A1[M x K1 (lda 714)]@B1 + h[M x 128]@B2 + cb) ----------
// BM=16*TM, BN=128, BK=32, 256 threads, TMx8 microtile, double-buffered, optional split-K
template<int TM, int SPLITK, bool RELU>
__global__ __launch_bounds__(256) void k_gemm2t(const float* A1, int K1, const float* A2,
                                                const float* B1, const float* B2,
                                                const float* bias, float* Cout, int M){
    constexpr int BM = TM*16;
    constexpr int AS = BM + 4;
    constexpr int ALOAD = BM*32/256;
    __shared__ float As[2][32*AS];
    __shared__ float Bs[2][32*132];
    int t = threadIdx.x;
    int bm0 = blockIdx.y * BM;
    int tx = t & 15, ty = t >> 4;
    int Ktot = K1 + D;
    int ntiles = (Ktot + 31) >> 5;
    int tper = (ntiles + SPLITK - 1) / SPLITK;
    int tbeg = blockIdx.z * tper;
    int tend = min(ntiles, tbeg + tper);
    int nt = tend - tbeg;

    float acc[TM][8];
    #pragma unroll
    for(int i=0;i<TM;++i)
        #pragma unroll
        for(int j=0;j<8;++j) acc[i][j]=0.f;

    float apre[ALOAD]; float bpre[16];
    auto loadA = [&](int kt){
        int k0 = (tbeg+kt)*32;
        #pragma unroll
        for(int i=0;i<ALOAD;++i){
            int idx = t + i*256;
            int row = idx >> 5; int kl = idx & 31;
            int kg = k0 + kl; int rg = bm0 + row;
            float v = 0.f;
            if(kg < K1)        v = A1[(size_t)rg*QWROW + kg];
            else if(kg < Ktot) v = A2[(size_t)rg*D + (kg-K1)];
            apre[i] = v;
        }
    };
    auto loadB = [&](int kt){
        int k0 = (tbeg+kt)*32;
        #pragma unroll
        for(int i=0;i<16;++i){
            int idx = t + i*256;
            int kr = idx >> 7; int col = idx & 127;
            int kg = k0 + kr;
            float v = 0.f;
            if(kg < K1)        v = B1[(size_t)kg*D + col];
            else if(kg < Ktot) v = B2[(size_t)(kg-K1)*D + col];
            bpre[i] = v;
        }
    };
    auto stash = [&](int buf){
        #pragma unroll
        for(int i=0;i<ALOAD;++i){
            int idx = t + i*256;
            int row = idx >> 5; int kl = idx & 31;
            As[buf][kl*AS + row] = apre[i];
        }
        #pragma unroll
        for(int i=0;i<16;++i){
            int idx = t + i*256;
            int kr = idx >> 7; int col = idx & 127;
            Bs[buf][kr*132 + col] = bpre[i];
        }
    };

    loadA(0); loadB(0); stash(0); __syncthreads();
    for(int kt=0; kt<nt; ++kt){
        int cur = kt & 1;
        if(kt+1 < nt){ loadA(kt+1); loadB(kt+1); }
        for(int k=0;k<32;++k){
            float av[TM];
            #pragma unroll
            for(int i=0;i<TM;++i) av[i] = As[cur][k*AS + ty*TM + i];
            float4 b0 = *(const float4*)(&Bs[cur][k*132 + tx*8]);
            float4 b1 = *(const float4*)(&Bs[cur][k*132 + tx*8 + 4]);
            float bv[8] = {b0.x,b0.y,b0.z,b0.w,b1.x,b1.y,b1.z,b1.w};
            #pragma unroll
            for(int i=0;i<TM;++i)
                #pragma unroll
                for(int j=0;j<8;++j) acc[i][j] += av[i]*bv[j];
        }
        if(kt+1 < nt){ stash(cur^1); __syncthreads(); }
    }

    #pragma unroll
    for(int i=0;i<TM;++i){
        int m = bm0 + ty*TM + i;
        if(SPLITK == 1){
            float4 o0, o1;
            float* o = (float*)&o0;
            #pragma unroll
            for(int j=0;j<8;++j){
                float v = acc[i][j] + bias[tx*8+j];
                if(RELU) v = fmaxf(v, 0.f);
                ((float*)&o0)[0]; // no-op to keep compiler happy
                if(j<4) ((float*)&o0)[j] = v; else ((float*)&o1)[j-4] = v;
            }
            *(float4*)(Cout + (size_t)m*D + tx*8)     = o0;
            *(float4*)(Cout + (size_t)m*D + tx*8 + 4) = o1;
        } else {
            float* dst = Cout + ((size_t)blockIdx.z*M + m)*D + tx*8;
            float4 o0 = {acc[i][0],acc[i][1],acc[i][2],acc[i][3]};
            float4 o1 = {acc[i][4],acc[i][5],acc[i][6],acc[i][7]};
            *(float4*)(dst)     = o0;
            *(float4*)(dst + 4) = o1;
        }
    }
}

// epilogue for split-K=3: z = relu(p0+p1+p2+cb)
__global__ void k_epi3(const float* p, const float* cb, float* z){
    int i = blockIdx.x*256 + threadIdx.x;
    if(i >= N0C*D) return;
    int n = i & 127;
    float v = p[i] + p[i + N0C*D] + p[i + 2*N0C*D] + cb[n];
    z[i] = fmaxf(v, 0.f);
}

// fused scores + masked softmax + av; one wave per node; packed av written into qw row
template<int K, int CMIN, int S>
__global__ __launch_bounds__(64) void k_attn(float* qwav,
    const float* times, const float* nbr_times, const float* nbr_feats,
    const int* nbr_mask, const int* nbr_local, const float* zbuf,
    const float* time_w, const float* time_b){
    int n = blockIdx.x; int lane = threadIdx.x;
    float qwreg[NHD][S], qb[NHD];
    #pragma unroll
    for(int h=0;h<NHD;++h){
        qb[h] = qwav[(size_t)n*QWROW + h*HSTR + KIN];
        #pragma unroll
        for(int s=0;s<S;++s){
            int c = CMIN + s*64 + lane;
            qwreg[h][s] = (c < KIN) ? qwav[(size_t)n*QWROW + h*HSTR + c] : 0.f;
        }
    }
    float tw[S], tb[S];
    #pragma unroll
    for(int s=0;s<S;++s){
        int c = CMIN + s*64 + lane;
        if(c >= D+E && c < KIN){ tw[s]=time_w[c-(D+E)]; tb[s]=time_b[c-(D+E)]; }
        else { tw[s]=0.f; tb[s]=0.f; }
    }
    float tn = times[n];
    float kinreg[K][S];
    float sval[NHD][K];
    #pragma unroll
    for(int k=0;k<K;++k){
        float dt = tn - nbr_times[(size_t)n*K + k];
        const float* ef = nbr_feats + (size_t)(n*K+k)*E;
        const float* zf = (CMIN==0) ? (zbuf + (size_t)(nbr_local[(size_t)n*K+k] - N0C)*D) : (const float*)0;
        float p0=0.f, p1=0.f;
        #pragma unroll
        for(int s=0;s<S;++s){
            int c = CMIN + s*64 + lane;
            float kv = 0.f;
            if(c < KIN){
                if(CMIN==0 && c < D)      kv = zf[c];
                else if(c < D+E)          kv = ef[c-D];
                else                      kv = __cosf(dt*tw[s] + tb[s]);
            }
            kinreg[k][s] = kv;
            p0 += kv * qwreg[0][s];
            p1 += kv * qwreg[1][s];
        }
        #pragma unroll
        for(int off=32; off; off>>=1){ p0 += __shfl_xor(p0, off); p1 += __shfl_xor(p1, off); }
        int mk = nbr_mask[(size_t)n*K + k];
        sval[0][k] = (mk>0) ? (p0 + qb[0])*0.125f : -1e9f;
        sval[1][k] = (mk>0) ? (p1 + qb[1])*0.125f : -1e9f;
    }
    float a[NHD][K];
    #pragma unroll
    for(int h=0;h<NHD;++h){
        float mx = -1e30f;
        #pragma unroll
        for(int k=0;k<K;++k) mx = fmaxf(mx, sval[h][k]);
        float z=0.f;
        #pragma unroll
        for(int k=0;k<K;++k){ float e = __expf(sval[h][k]-mx); a[h][k]=e; z+=e; }
        float inv = 1.f/z;
        #pragma unroll
        for(int k=0;k<K;++k) a[h][k]*=inv;
    }
    // write packed av into the same qw row: col h*(KIN-CMIN) + (c-CMIN)
    #pragma unroll
    for(int h=0;h<NHD;++h)
      #pragma unroll
      for(int s=0;s<S;++s){
        int c = CMIN + s*64 + lane;
        if(c < KIN){
            float v=0.f;
            #pragma unroll
            for(int k=0;k<K;++k) v += a[h][k]*kinreg[k][s];
            qwav[(size_t)n*QWROW + h*(KIN-CMIN) + (c-CMIN)] = v;
        }
      }
}

// link prediction: both (src,dst) and (src,neg) per block
__global__ __launch_bounds__(128) void k_linkpred(const float* z0,
      const int* src,const int* dst,const int* neg,
      const float* Ws,const float* bs,const float* Wd,const float* bd,
      const float* Wo,const float* bo, float* out){
    __shared__ float zs[D], zd[D], zn[D];
    __shared__ float red[4];
    int b = blockIdx.x; int d = threadIdx.x;
    zs[d] = z0[(size_t)src[b]*D + d];
    zd[d] = z0[(size_t)dst[b]*D + d];
    zn[d] = z0[(size_t)neg[b]*D + d];
    __syncthreads();
    float ss=0.f, sdd=0.f, snn=0.f;
    for(int c=0;c<D;++c){
        float w1 = Ws[c*D + d], w2 = Wd[c*D + d];
        ss  += zs[c]*w1; sdd += zd[c]*w2; snn += zn[c]*w2;
    }
    float bb = bs[d] + bd[d];
    float h1 = fmaxf(ss + sdd + bb, 0.f);
    float h2 = fmaxf(ss + snn + bb, 0.f);
    float w = Wo[d];
    float v1 = h1*w, v2 = h2*w;
    #pragma unroll
    for(int off=32; off; off>>=1){ v1 += __shfl_xor(v1,off); v2 += __shfl_xor(v2,off); }
    int wid = d>>6;
    if((d&63)==0){ red[wid*2]=v1; red[wid*2+1]=v2; }
    __syncthreads();
    if(d==0){
        out[b]       = sigmoidf_(red[0]+red[2] + bo[0]);
        out[BSZ + b] = sigmoidf_(red[1]+red[3] + bo[0]);
    }
}

extern "C" void kernel_launch(void* const* d_in, const int* in_sizes, int n_in,
                              void* d_out, int out_size, void* d_ws, size_t ws_size,
                              hipStream_t stream) {
    const float* memory  = (const float*)d_in[0];
    const float* time_w  = (const float*)d_in[1];
    const float* time_b  = (const float*)d_in[2];
    const float* gWih    = (const float*)d_in[3];
    const float* gbih    = (const float*)d_in[4];
    const float* gWhh    = (const float*)d_in[5];
    const float* gbhh    = (const float*)d_in[6];
    const float* Wq0=(const float*)d_in[7],  *bq0=(const float*)d_in[8];
    const float* Wk0=(const float*)d_in[9],  *bk0=(const float*)d_in[10];
    const float* Wv0=(const float*)d_in[11], *bv0=(const float*)d_in[12];
    const float* Wo0=(const float*)d_in[13], *bo0=(const float*)d_in[14];
    const float* Wq1=(const float*)d_in[15], *bq1=(const float*)d_in[16];
    const float* Wk1=(const float*)d_in[17], *bk1=(const float*)d_in[18];
    const float* Wv1=(const float*)d_in[19], *bv1=(const float*)d_in[20];
    const float* Wo1=(const float*)d_in[21], *bo1=(const float*)d_in[22];
    const float* lpWs=(const float*)d_in[23], *lpbs=(const float*)d_in[24];
    const float* lpWd=(const float*)d_in[25], *lpbd=(const float*)d_in[26];
    const float* lpWo=(const float*)d_in[27], *lpbo=(const float*)d_in[28];
    const float* msgs    = (const float*)d_in[29];
    const float* times0  = (const float*)d_in[30];
    const float* ntimes0 = (const float*)d_in[31];
    const float* nfeats0 = (const float*)d_in[32];
    const float* times1  = (const float*)d_in[33];
    const float* ntimes1 = (const float*)d_in[34];
    const float* nfeats1 = (const float*)d_in[35];
    const int* msg_nids  = (const int*)d_in[36];
    const int* seed0     = (const int*)d_in[37];
    const int* seed1     = (const int*)d_in[38];
    const int* nbr_local0= (const int*)d_in[39];
    const int* nbr_mask0 = (const int*)d_in[40];
    const int* nbr_mask1 = (const int*)d_in[41];
    const int* src       = (const int*)d_in[42];
    const int* dst       = (const int*)d_in[43];
    const int* neg       = (const int*)d_in[44];

    char* ws = (char*)d_ws;
    size_t off = 0;
    auto alloc = [&](size_t bytes)->char*{
        char* p = ws + off;
        off += (bytes + 255) & ~(size_t)255;
        return p;
    };
    int*   map  = (int*)  alloc((size_t)NNC*4);
    float* upd  = (float*)alloc((size_t)MC*D*4);
    float* h1   = (float*)alloc((size_t)N1C*D*4);
    float* qw1  = (float*)alloc((size_t)N1C*QWROW*4);   // also holds packed av1 after attn
    float* z1   = (float*)alloc((size_t)N1C*D*4);
    float* h0   = (float*)alloc((size_t)N0C*D*4);
    float* qw0  = (float*)alloc((size_t)N0C*QWROW*4);   // also holds packed av0
    float* z0   = (float*)alloc((size_t)N0C*D*4);
    float* part = (float*)alloc((size_t)3*N0C*D*4);     // split-K partials
    float* qc0  = (float*)alloc(512);
    float* qc1  = (float*)alloc(512);
    float* cb0  = (float*)alloc(512);
    float* cb1  = (float*)alloc(512);
    float* WF0  = (float*)alloc((size_t)D*QWROW*4);
    float* WF1  = (float*)alloc((size_t)D*QWROW*4);
    float* cF0  = (float*)alloc((size_t)QWROW*4);
    float* cF1  = (float*)alloc((size_t)QWROW*4);
    float* Wvo0 = (float*)alloc((size_t)2*KIN*D*4);          // 712 rows
    float* Wvo1 = (float*)alloc((size_t)2*(KIN-128)*D*4);    // 456 rows
    float* outp = (float*)d_out;

    // precompute
    k_pre_small<<<1,128,0,stream>>>(time_b, Wq0,bq0,Wq1,bq1, bv0,Wo0,bo0, bv1,Wo1,bo1,
                                    qc0,qc1,cb0,cb1);
    k_wf<<<2*QWROW,128,0,stream>>>(Wq0,Wk0,bk0,qc0, Wq1,Wk1,bk1,qc1, WF0,cF0,WF1,cF1);
    k_wvo<<<2*KIN,128,0,stream>>>(Wv0,Wo0,Wvo0,0);
    k_wvo<<<2*(KIN-128),128,0,stream>>>(Wv1,Wo1,Wvo1,128);

    // GRU memory update
    k_map_init<<<(NNC+255)/256,256,0,stream>>>(map);
    k_map_scatter<<<MC/256,256,0,stream>>>(msg_nids, map);
    k_gru<<<MC/8,384,0,stream>>>(msgs, memory, msg_nids, gWih,gbih,gWhh,gbhh, upd);

    // gather node states (both hops, one launch)
    k_gatherf<<<((N1C+N0C)*D)/256,256,0,stream>>>(seed1, seed0, map, memory, upd, h1, h0);

    // GEMM1 both hops fused
    {
        dim3 g(6, N1C/128 + N0C/128);
        k_gemm1f<<<g,256,0,stream>>>(h1, WF1, cF1, qw1, h0, WF0, cF0, qw0);
    }
    // hop 1 attention + GEMM2 (TM=4 -> BM=64, 480 blocks)
    k_attn<K1C,128,4><<<N1C,64,0,stream>>>(qw1, times1, ntimes1, nfeats1,
                                           nbr_mask1, (const int*)0, (const float*)0,
                                           time_w, time_b);
    {
        dim3 g(1, N1C/64, 1);
        k_gemm2t<4,1,true><<<g,256,0,stream>>>(qw1, 2*(KIN-128), h1, Wvo1, Wo1 + D*D, cb1, z1, N1C);
    }
    // hop 0 attention + GEMM2 (TM=2 -> BM=32, split-K=3 -> 576 blocks) + epilogue
    k_attn<K0C,0,6><<<N0C,64,0,stream>>>(qw0, times0, ntimes0, nfeats0,
                                         nbr_mask0, nbr_local0, z1,
                                         time_w, time_b);
    {
        dim3 g(1, N0C/32, 3);
        k_gemm2t<2,3,false><<<g,256,0,stream>>>(qw0, 2*KIN, h0, Wvo0, Wo0 + D*D, cb0, part, N0C);
    }
    k_epi3<<<(N0C*D)/256,256,0,stream>>>(part, cb0, z0);

    // link prediction
    k_linkpred<<<BSZ,128,0,stream>>>(z0, src,dst,neg, lpWs,lpbs,lpWd,lpbd, lpWo,lpbo, outp);
}

// Round 4
// 822.965 us; speedup vs baseline: 1.5181x; 1.0894x over previous
//
#include <hip/hip_runtime.h>
#include <math.h>

// ---- problem constants ----
#define D    128
#define TT   128
#define E    100
#define NHD  2
#define BSZ  2048
#define N0C  6144
#define K0C  5
#define N1C  30720
#define K1C  10
#define NNC  200000
#define MC   4096
#define MSG  484
#define KIN  356        // D+E+T
#define HSTR 357        // per-head qw stride (356 cols + qb)
#define QWROW 714       // 2*HSTR

typedef __attribute__((ext_vector_type(8))) short short8v;   // 8 bf16 (4 VGPRs)
typedef __attribute__((ext_vector_type(4))) float f32x4;

__device__ __forceinline__ float sigmoidf_(float x){ return 1.f/(1.f+__expf(-x)); }
__device__ __forceinline__ unsigned short f2b(float f){
    unsigned int x = __float_as_uint(f);
    unsigned int r = (x + 0x7fffu + ((x>>16)&1u)) >> 16;
    return (unsigned short)r;
}
__device__ __forceinline__ float b2f(unsigned short u){
    return __uint_as_float(((unsigned int)u)<<16);
}

// ---------- precompute: qc (time-const query bias), cb (fused out bias) ----------
__global__ void k_pre_small(const float* time_b,
                            const float* Wq0,const float* bq0,const float* Wq1,const float* bq1,
                            const float* bv0,const float* Wo0,const float* bo0,
                            const float* bv1,const float* Wo1,const float* bo1,
                            float* qc0, float* qc1, float* cb0, float* cb1){
    __shared__ float cosb[TT];
    int j = threadIdx.x; // 128 threads
    cosb[j] = cosf(time_b[j]);
    __syncthreads();
    float a0=bq0[j], a1=bq1[j];
    for(int t=0;t<TT;++t){ a0 += cosb[t]*Wq0[(D+t)*D + j]; a1 += cosb[t]*Wq1[(D+t)*D + j]; }
    qc0[j]=a0; qc1[j]=a1;
    float c0=bo0[j], c1=bo1[j];
    for(int jp=0;jp<D;++jp){ c0 += bv0[jp]*Wo0[jp*D + j]; c1 += bv1[jp]*Wo1[jp*D + j]; }
    cb0[j]=c0; cb1[j]=c1;
}

// WFb[k][h*357+c] = sum_d Wq[k][h*64+d] * (c<356 ? Wk[c][h*64+d] : bk[h*64+d])   (bf16)
__global__ void k_wf(const float* Wq0,const float* Wk0,const float* bk0,const float* qc0,
                     const float* Wq1,const float* Wk1,const float* bk1,const float* qc1,
                     unsigned short* WF0, float* cF0, unsigned short* WF1, float* cF1){
    int l = blockIdx.x / QWROW; int col = blockIdx.x % QWROW;
    int h = col / HSTR; int c = col % HSTR;
    const float* Wq = l? Wq1:Wq0; const float* Wk = l? Wk1:Wk0;
    const float* bk = l? bk1:bk0; const float* qc = l? qc1:qc0;
    unsigned short* WF = l? WF1:WF0; float* cF = l? cF1:cF0;
    int k = threadIdx.x;
    float a = 0.f;
    for(int d=0; d<64; ++d){
        float wkv = (c < KIN) ? Wk[c*D + h*64+d] : bk[h*64+d];
        a += Wq[k*D + h*64+d] * wkv;
    }
    WF[(size_t)k*QWROW + col] = f2b(a);
    if(k==0){
        float s=0.f;
        for(int d=0; d<64; ++d){
            float wkv = (c < KIN) ? Wk[c*D + h*64+d] : bk[h*64+d];
            s += qc[h*64+d]*wkv;
        }
        cF[col] = s;
    }
}

// Bcat (bf16): rows [0, 2*span) = fused Wvo rows (h*span + (c-cmin));
//              rows [2*span, 2*span+128) = Wo[D + r][j]  (bottom half of Wo)
__global__ void k_bcat(const float* Wv, const float* Wo, unsigned short* Bcat, int cmin){
    int span = KIN - cmin; int rows = 2*span;
    int r = blockIdx.x; int j = threadIdx.x;
    float a;
    if(r < rows){
        int h = r/span; int c = cmin + (r - h*span);
        a = 0.f;
        for(int d=0; d<64; ++d) a += Wv[c*D + h*64+d] * Wo[(h*64+d)*D + j];
    } else {
        a = Wo[(size_t)(D + (r - rows))*D + j];
    }
    Bcat[(size_t)r*D + j] = f2b(a);
}

// ---------- GRU memory update on M rows ----------
__global__ void k_map_init(int* map){ int i = blockIdx.x*256+threadIdx.x; if(i<NNC) map[i] = -1; }
__global__ void k_map_scatter(const int* msg_nids, int* map){
    int i = blockIdx.x*256+threadIdx.x; if(i<MC) map[msg_nids[i]] = i;
}

// 8 msgs/block, 384 threads (gate g = tid>>7 in parallel), two-phase
__global__ __launch_bounds__(384) void k_gru(const float* msgs, const float* memory, const int* msg_nids,
                      const float* Wih, const float* bih, const float* Whh, const float* bhh,
                      float* upd){
    __shared__ float xs[8*MSG];
    __shared__ float hsm[8*D];
    __shared__ float si[3*128*8];
    __shared__ float sh[3*128*8];
    int blk = blockIdx.x; int tid = threadIdx.x;
    const float* mrow = msgs + (size_t)blk*8*MSG;
    for(int i=tid; i<8*MSG; i+=384) xs[i] = mrow[i];
    for(int i=tid; i<8*D; i+=384){
        int m = i>>7; int c = i&127;
        hsm[i] = memory[(size_t)msg_nids[blk*8+m]*D + c];
    }
    __syncthreads();
    int g = tid>>7, d = tid&127;
    float ai[8], ah[8];
    #pragma unroll
    for(int m=0;m<8;++m){ ai[m]=0.f; ah[m]=0.f; }
    const float* wi = Wih + (size_t)(g*D+d)*MSG;
    for(int c=0;c<MSG;c+=4){
        float4 w4 = *(const float4*)(wi + c);
        #pragma unroll
        for(int m=0;m<8;++m){
            float4 x4 = *(const float4*)(xs + m*MSG + c);
            ai[m] += w4.x*x4.x + w4.y*x4.y + w4.z*x4.z + w4.w*x4.w;
        }
    }
    const float* wh = Whh + (size_t)(g*D+d)*D;
    for(int c=0;c<D;c+=4){
        float4 w4 = *(const float4*)(wh + c);
        #pragma unroll
        for(int m=0;m<8;++m){
            float4 h4 = *(const float4*)(hsm + m*D + c);
            ah[m] += w4.x*h4.x + w4.y*h4.y + w4.z*h4.z + w4.w*h4.w;
        }
    }
    float bi = bih[g*D+d], bh = bhh[g*D+d];
    #pragma unroll
    for(int m=0;m<8;++m){ si[tid*8+m] = ai[m]+bi; sh[tid*8+m] = ah[m]+bh; }
    __syncthreads();
    if(tid < 128){
        #pragma unroll
        for(int m=0;m<8;++m){
            float ir = si[(0*128+tid)*8+m], hr = sh[(0*128+tid)*8+m];
            float iz = si[(1*128+tid)*8+m], hz = sh[(1*128+tid)*8+m];
            float in_= si[(2*128+tid)*8+m], hn = sh[(2*128+tid)*8+m];
            float r = sigmoidf_(ir+hr);
            float u = sigmoidf_(iz+hz);
            float nn = tanhf(in_ + r*hn);
            upd[(size_t)(blk*8+m)*D + tid] = (1.f-u)*nn + u*hsm[m*D+tid];
        }
    }
}

// fused gather for both hops: writes bf16 h into hb* and into trailing cols of Acat*
__global__ void k_gatherf(const int* seed1,const int* seed0,const int* map,
                          const float* memory,const float* upd,
                          unsigned short* hb1, unsigned short* acat1,
                          unsigned short* hb0, unsigned short* acat0){
    int i = blockIdx.x*256 + threadIdx.x;
    const int total1 = N1C*D;
    int li; const int* seed; unsigned short* hb; unsigned short* acat; int ldav, hoff;
    if(i < total1){ li=i; seed=seed1; hb=hb1; acat=acat1; ldav=584; hoff=456; }
    else { li = i - total1; if(li >= N0C*D) return; seed=seed0; hb=hb0; acat=acat0; ldav=840; hoff=712; }
    int row = li>>7, c = li&127;
    int sid = seed[row];
    int mi = map[sid];
    float v = (mi>=0) ? upd[(size_t)mi*D + c] : memory[(size_t)sid*D + c];
    unsigned short u = f2b(v);
    hb[li] = u;
    acat[(size_t)row*ldav + hoff + c] = u;
}

// ---------- bf16 MFMA GEMM: C[M x N] = op(A[M x K] @ B[K x N] + bias) ----------
// BM x 64 tile, BK=64, 256 threads (4 waves), wave = BM/4 rows x 64 cols
// A row-major bf16 (lda even), B row-major bf16, bias f32, C f32 or bf16
template<int BM, bool RELU, bool OUTF32>
__global__ __launch_bounds__(256) void k_gmm(const unsigned short* A, int lda,
                                             const unsigned short* B, int ldb,
                                             const float* bias, void* Cp, int ldc,
                                             int K, int N){
    constexpr int ASTR = 72;
    constexpr int BSTR = 72;
    constexpr int RPW = BM/4;       // rows per wave
    constexpr int RT  = RPW/16;     // 16-row tiles per wave
    constexpr int AIT = BM/32;      // A staging iterations
    __shared__ unsigned short As[BM*ASTR];
    __shared__ unsigned short Bs[64*BSTR];
    int t = threadIdx.x;
    int wave = t>>6, lane = t&63;
    int l15 = lane&15, l4 = lane>>4;
    int m0 = blockIdx.y*BM, n0 = blockIdx.x*64;
    f32x4 acc[RT][4];
    #pragma unroll
    for(int rt=0;rt<RT;++rt)
        #pragma unroll
        for(int ct=0;ct<4;++ct) acc[rt][ct] = (f32x4){0.f,0.f,0.f,0.f};

    int ntiles = (K+63)>>6;
    for(int kt=0; kt<ntiles; ++kt){
        int k0 = kt<<6;
        if(kt) __syncthreads();
        // stage A: BM rows x 64 k (16B chunks; K%8==0 so chunks are all-or-none)
        #pragma unroll
        for(int i=0;i<AIT;++i){
            int idx = t + i*256;
            int row = idx>>3; int kc = (idx&7)*8;
            uint4 v = {0u,0u,0u,0u};
            if(k0+kc < K) v = *(const uint4*)(A + (size_t)(m0+row)*lda + k0 + kc);
            *(uint4*)&As[row*ASTR + kc] = v;
        }
        // stage B transposed: Bs[n][k]
        {
            int n = t&63; int kb = (t>>6)*16;
            int ng = n0+n;
            #pragma unroll
            for(int j=0;j<16;++j){
                int kg = k0 + kb + j;
                unsigned short v = (kg<K && ng<N) ? B[(size_t)kg*ldb + ng] : (unsigned short)0;
                Bs[n*BSTR + kb + j] = v;
            }
        }
        __syncthreads();
        #pragma unroll
        for(int kk=0; kk<64; kk+=32){
            short8v bfr[4];
            #pragma unroll
            for(int ct=0;ct<4;++ct)
                bfr[ct] = *(const short8v*)&Bs[(ct*16+l15)*BSTR + kk + l4*8];
            #pragma unroll
            for(int rt=0;rt<RT;++rt){
                short8v afr = *(const short8v*)&As[(wave*RPW + rt*16 + l15)*ASTR + kk + l4*8];
                #pragma unroll
                for(int ct=0;ct<4;++ct)
                    acc[rt][ct] = __builtin_amdgcn_mfma_f32_16x16x32_bf16(afr, bfr[ct], acc[rt][ct], 0,0,0);
            }
        }
    }
    // epilogue: D layout col=lane&15, row=(lane>>4)*4+reg
    #pragma unroll
    for(int rt=0;rt<RT;++rt){
        #pragma unroll
        for(int ct=0;ct<4;++ct){
            int col = n0 + ct*16 + l15;
            if(col < N){
                float bb = bias[col];
                #pragma unroll
                for(int r=0;r<4;++r){
                    int row = m0 + wave*RPW + rt*16 + l4*4 + r;
                    float v = acc[rt][ct][r] + bb;
                    if(RELU) v = fmaxf(v, 0.f);
                    if(OUTF32) ((float*)Cp)[(size_t)row*ldc + col] = v;
                    else ((unsigned short*)Cp)[(size_t)row*ldc + col] = f2b(v);
                }
            }
        }
    }
}

// fused scores + masked softmax + av; one wave per node
// reads qw (bf16), writes packed av (bf16) into Acat cols [0, 2*(KIN-CMIN))
template<int K, int CMIN, int S>
__global__ __launch_bounds__(64) void k_attn(const unsigned short* qwb,
    unsigned short* avout, int ldav,
    const float* times, const float* nbr_times, const float* nbr_feats,
    const int* nbr_mask, const int* nbr_local, const unsigned short* zbuf,
    const float* time_w, const float* time_b){
    int n = blockIdx.x; int lane = threadIdx.x;
    constexpr int SPAN = KIN - CMIN;
    float qwreg[NHD][S], qb[NHD];
    #pragma unroll
    for(int h=0;h<NHD;++h){
        qb[h] = b2f(qwb[(size_t)n*QWROW + h*HSTR + KIN]);
        #pragma unroll
        for(int s=0;s<S;++s){
            int c = CMIN + s*64 + lane;
            qwreg[h][s] = (c < KIN) ? b2f(qwb[(size_t)n*QWROW + h*HSTR + c]) : 0.f;
        }
    }
    float tw[S], tb[S];
    #pragma unroll
    for(int s=0;s<S;++s){
        int c = CMIN + s*64 + lane;
        if(c >= D+E && c < KIN){ tw[s]=time_w[c-(D+E)]; tb[s]=time_b[c-(D+E)]; }
        else { tw[s]=0.f; tb[s]=0.f; }
    }
    float tn = times[n];
    float kinreg[K][S];
    float sval[NHD][K];
    #pragma unroll
    for(int k=0;k<K;++k){
        float dt = tn - nbr_times[(size_t)n*K + k];
        const float* ef = nbr_feats + (size_t)(n*K+k)*E;
        const unsigned short* zf = (CMIN==0) ? (zbuf + (size_t)(nbr_local[(size_t)n*K+k] - N0C)*D) : (const unsigned short*)0;
        float p0=0.f, p1=0.f;
        #pragma unroll
        for(int s=0;s<S;++s){
            int c = CMIN + s*64 + lane;
            float kv = 0.f;
            if(c < KIN){
                if(CMIN==0 && c < D)      kv = b2f(zf[c]);
                else if(c < D+E)          kv = ef[c-D];
                else                      kv = __cosf(dt*tw[s] + tb[s]);
            }
            kinreg[k][s] = kv;
            p0 += kv * qwreg[0][s];
            p1 += kv * qwreg[1][s];
        }
        #pragma unroll
        for(int off=32; off; off>>=1){ p0 += __shfl_xor(p0, off); p1 += __shfl_xor(p1, off); }
        int mk = nbr_mask[(size_t)n*K + k];
        sval[0][k] = (mk>0) ? (p0 + qb[0])*0.125f : -1e9f;
        sval[1][k] = (mk>0) ? (p1 + qb[1])*0.125f : -1e9f;
    }
    float a[NHD][K];
    #pragma unroll
    for(int h=0;h<NHD;++h){
        float mx = -1e30f;
        #pragma unroll
        for(int k=0;k<K;++k) mx = fmaxf(mx, sval[h][k]);
        float z=0.f;
        #pragma unroll
        for(int k=0;k<K;++k){ float e = __expf(sval[h][k]-mx); a[h][k]=e; z+=e; }
        float inv = 1.f/z;
        #pragma unroll
        for(int k=0;k<K;++k) a[h][k]*=inv;
    }
    #pragma unroll
    for(int h=0;h<NHD;++h)
      #pragma unroll
      for(int s=0;s<S;++s){
        int c = CMIN + s*64 + lane;
        if(c < KIN){
            float v=0.f;
            #pragma unroll
            for(int k=0;k<K;++k) v += a[h][k]*kinreg[k][s];
            avout[(size_t)n*ldav + h*SPAN + (c-CMIN)] = f2b(v);
        }
      }
}

// link prediction: both (src,dst) and (src,neg) per block
__global__ __launch_bounds__(128) void k_linkpred(const float* z0,
      const int* src,const int* dst,const int* neg,
      const float* Ws,const float* bs,const float* Wd,const float* bd,
      const float* Wo,const float* bo, float* out){
    __shared__ float zs[D], zd[D], zn[D];
    __shared__ float red[4];
    int b = blockIdx.x; int d = threadIdx.x;
    zs[d] = z0[(size_t)src[b]*D + d];
    zd[d] = z0[(size_t)dst[b]*D + d];
    zn[d] = z0[(size_t)neg[b]*D + d];
    __syncthreads();
    float ss=0.f, sdd=0.f, snn=0.f;
    for(int c=0;c<D;++c){
        float w1 = Ws[c*D + d], w2 = Wd[c*D + d];
        ss  += zs[c]*w1; sdd += zd[c]*w2; snn += zn[c]*w2;
    }
    float bb = bs[d] + bd[d];
    float h1 = fmaxf(ss + sdd + bb, 0.f);
    float h2 = fmaxf(ss + snn + bb, 0.f);
    float w = Wo[d];
    float v1 = h1*w, v2 = h2*w;
    #pragma unroll
    for(int off=32; off; off>>=1){ v1 += __shfl_xor(v1,off); v2 += __shfl_xor(v2,off); }
    int wid = d>>6;
    if((d&63)==0){ red[wid*2]=v1; red[wid*2+1]=v2; }
    __syncthreads();
    if(d==0){
        out[b]       = sigmoidf_(red[0]+red[2] + bo[0]);
        out[BSZ + b] = sigmoidf_(red[1]+red[3] + bo[0]);
    }
}

extern "C" void kernel_launch(void* const* d_in, const int* in_sizes, int n_in,
                              void* d_out, int out_size, void* d_ws, size_t ws_size,
                              hipStream_t stream) {
    const float* memory  = (const float*)d_in[0];
    const float* time_w  = (const float*)d_in[1];
    const float* time_b  = (const float*)d_in[2];
    const float* gWih    = (const float*)d_in[3];
    const float* gbih    = (const float*)d_in[4];
    const float* gWhh    = (const float*)d_in[5];
    const float* gbhh    = (const float*)d_in[6];
    const float* Wq0=(const float*)d_in[7],  *bq0=(const float*)d_in[8];
    const float* Wk0=(const float*)d_in[9],  *bk0=(const float*)d_in[10];
    const float* Wv0=(const float*)d_in[11], *bv0=(const float*)d_in[12];
    const float* Wo0=(const float*)d_in[13], *bo0=(const float*)d_in[14];
    const float* Wq1=(const float*)d_in[15], *bq1=(const float*)d_in[16];
    const float* Wk1=(const float*)d_in[17], *bk1=(const float*)d_in[18];
    const float* Wv1=(const float*)d_in[19], *bv1=(const float*)d_in[20];
    const float* Wo1=(const float*)d_in[21], *bo1=(const float*)d_in[22];
    const float* lpWs=(const float*)d_in[23], *lpbs=(const float*)d_in[24];
    const float* lpWd=(const float*)d_in[25], *lpbd=(const float*)d_in[26];
    const float* lpWo=(const float*)d_in[27], *lpbo=(const float*)d_in[28];
    const float* msgs    = (const float*)d_in[29];
    const float* times0  = (const float*)d_in[30];
    const float* ntimes0 = (const float*)d_in[31];
    const float* nfeats0 = (const float*)d_in[32];
    const float* times1  = (const float*)d_in[33];
    const float* ntimes1 = (const float*)d_in[34];
    const float* nfeats1 = (const float*)d_in[35];
    const int* msg_nids  = (const int*)d_in[36];
    const int* seed0     = (const int*)d_in[37];
    const int* seed1     = (const int*)d_in[38];
    const int* nbr_local0= (const int*)d_in[39];
    const int* nbr_mask0 = (const int*)d_in[40];
    const int* nbr_mask1 = (const int*)d_in[41];
    const int* src       = (const int*)d_in[42];
    const int* dst       = (const int*)d_in[43];
    const int* neg       = (const int*)d_in[44];

    char* ws = (char*)d_ws;
    size_t off = 0;
    auto alloc = [&](size_t bytes)->char*{
        char* p = ws + off;
        off += (bytes + 255) & ~(size_t)255;
        return p;
    };
    int*   map   = (int*)  alloc((size_t)NNC*4);
    float* upd   = (float*)alloc((size_t)MC*D*4);
    unsigned short* hb1   = (unsigned short*)alloc((size_t)N1C*D*2);
    unsigned short* qwb1  = (unsigned short*)alloc((size_t)N1C*QWROW*2);
    unsigned short* acat1 = (unsigned short*)alloc((size_t)N1C*584*2);
    unsigned short* zb1   = (unsigned short*)alloc((size_t)N1C*D*2);
    unsigned short* hb0   = (unsigned short*)alloc((size_t)N0C*D*2);
    unsigned short* qwb0  = (unsigned short*)alloc((size_t)N0C*QWROW*2);
    unsigned short* acat0 = (unsigned short*)alloc((size_t)N0C*840*2);
    float* z0    = (float*)alloc((size_t)N0C*D*4);
    float* qc0   = (float*)alloc(512);
    float* qc1   = (float*)alloc(512);
    float* cb0   = (float*)alloc(512);
    float* cb1   = (float*)alloc(512);
    unsigned short* WFb0 = (unsigned short*)alloc((size_t)D*QWROW*2);
    unsigned short* WFb1 = (unsigned short*)alloc((size_t)D*QWROW*2);
    float* cF0   = (float*)alloc((size_t)QWROW*4);
    float* cF1   = (float*)alloc((size_t)QWROW*4);
    unsigned short* Bcat1 = (unsigned short*)alloc((size_t)584*D*2);
    unsigned short* Bcat0 = (unsigned short*)alloc((size_t)840*D*2);
    float* outp = (float*)d_out;

    // precompute
    k_pre_small<<<1,128,0,stream>>>(time_b, Wq0,bq0,Wq1,bq1, bv0,Wo0,bo0, bv1,Wo1,bo1,
                                    qc0,qc1,cb0,cb1);
    k_wf<<<2*QWROW,128,0,stream>>>(Wq0,Wk0,bk0,qc0, Wq1,Wk1,bk1,qc1, WFb0,cF0,WFb1,cF1);
    k_bcat<<<584,128,0,stream>>>(Wv1, Wo1, Bcat1, 128);   // 2*228 + 128 rows
    k_bcat<<<840,128,0,stream>>>(Wv0, Wo0, Bcat0, 0);     // 2*356 + 128 rows

    // GRU memory update
    k_map_init<<<(NNC+255)/256,256,0,stream>>>(map);
    k_map_scatter<<<MC/256,256,0,stream>>>(msg_nids, map);
    k_gru<<<MC/8,384,0,stream>>>(msgs, memory, msg_nids, gWih,gbih,gWhh,gbhh, upd);

    // gather node states (both hops, one launch) -> bf16
    k_gatherf<<<((N1C+N0C)*D)/256,256,0,stream>>>(seed1, seed0, map, memory, upd,
                                                  hb1, acat1, hb0, acat0);

    // GEMM1 (MFMA): qw = h @ WF + cF
    k_gmm<128,false,false><<<dim3(12, N1C/128),256,0,stream>>>(hb1,128, WFb1,QWROW, cF1, qwb1,QWROW, 128, QWROW);
    k_gmm<128,false,false><<<dim3(12, N0C/128),256,0,stream>>>(hb0,128, WFb0,QWROW, cF0, qwb0,QWROW, 128, QWROW);

    // hop 1 attention -> av into acat1 cols [0,456)
    k_attn<K1C,128,4><<<N1C,64,0,stream>>>(qwb1, acat1, 584, times1, ntimes1, nfeats1,
                                           nbr_mask1, (const int*)0, (const unsigned short*)0,
                                           time_w, time_b);
    // GEMM2 hop1 (MFMA): z1 = relu(acat1 @ Bcat1 + cb1) -> bf16
    k_gmm<128,true,false><<<dim3(2, N1C/128),256,0,stream>>>(acat1,584, Bcat1,D, cb1, zb1,D, 584, D);

    // hop 0 attention -> av into acat0 cols [0,712)
    k_attn<K0C,0,6><<<N0C,64,0,stream>>>(qwb0, acat0, 840, times0, ntimes0, nfeats0,
                                         nbr_mask0, nbr_local0, zb1,
                                         time_w, time_b);
    // GEMM2 hop0 (MFMA): z0 = relu(acat0 @ Bcat0 + cb0) -> f32
    k_gmm<64,true,true><<<dim3(2, N0C/64),256,0,stream>>>(acat0,840, Bcat0,D, cb0, z0,D, 840, D);

    // link prediction
    k_linkpred<<<BSZ,128,0,stream>>>(z0, src,dst,neg, lpWs,lpbs,lpWd,lpbd, lpWo,lpbo, outp);
}

// Round 5
// 779.369 us; speedup vs baseline: 1.6031x; 1.0559x over previous
//
#include <hip/hip_runtime.h>
#include <math.h>

// ---- problem constants ----
#define D    128
#define TT   128
#define E    100
#define NHD  2
#define BSZ  2048
#define N0C  6144
#define K0C  5
#define N1C  30720
#define K1C  10
#define NNC  200000
#define MC   4096
#define MSG  484
#define KIN  356        // D+E+T

typedef __attribute__((ext_vector_type(8))) short short8v;   // 8 bf16 (4 VGPRs)
typedef __attribute__((ext_vector_type(4))) float f32x4;

__device__ __forceinline__ float sigmoidf_(float x){ return 1.f/(1.f+__expf(-x)); }
__device__ __forceinline__ unsigned short f2b(float f){
    unsigned int x = __float_as_uint(f);
    unsigned int r = (x + 0x7fffu + ((x>>16)&1u)) >> 16;
    return (unsigned short)r;
}
__device__ __forceinline__ float b2f(unsigned short u){
    return __uint_as_float(((unsigned int)u)<<16);
}

// ---------- precompute: qc (time-const query bias), cb (fused out bias) ----------
__global__ void k_pre_small(const float* time_b,
                            const float* Wq0,const float* bq0,const float* Wq1,const float* bq1,
                            const float* bv0,const float* Wo0,const float* bo0,
                            const float* bv1,const float* Wo1,const float* bo1,
                            float* qc0, float* qc1, float* cb0, float* cb1){
    __shared__ float cosb[TT];
    int j = threadIdx.x; // 128 threads
    cosb[j] = cosf(time_b[j]);
    __syncthreads();
    float a0=bq0[j], a1=bq1[j];
    for(int t=0;t<TT;++t){ a0 += cosb[t]*Wq0[(D+t)*D + j]; a1 += cosb[t]*Wq1[(D+t)*D + j]; }
    qc0[j]=a0; qc1[j]=a1;
    float c0=bo0[j], c1=bo1[j];
    for(int jp=0;jp<D;++jp){ c0 += bv0[jp]*Wo0[jp*D + j]; c1 += bv1[jp]*Wo1[jp*D + j]; }
    cb0[j]=c0; cb1[j]=c1;
}

// WF (bf16), layout per layer: head h at col h*hstr + (c-cmin), c in [cmin,356]
// (c==356 is the qb column = bk-derived); hstr = (356-cmin)+2, width = 2*hstr
__global__ void k_wf(const float* Wq,const float* Wk,const float* bk,const float* qc,
                     unsigned short* WF, float* cF, int cmin){
    int span1 = 357 - cmin;              // number of c values (incl qb col)
    int hstr  = (356 - cmin) + 2;
    int idx = blockIdx.x;
    int h = idx / span1; int cl = idx % span1;
    int c = cmin + cl;
    int col = h*hstr + cl;
    int width = 2*hstr;
    int k = threadIdx.x;
    float a = 0.f;
    for(int d=0; d<64; ++d){
        float wkv = (c < KIN) ? Wk[c*D + h*64+d] : bk[h*64+d];
        a += Wq[k*D + h*64+d] * wkv;
    }
    WF[(size_t)k*width + col] = f2b(a);
    if(k==0){
        float s=0.f;
        for(int d=0; d<64; ++d){
            float wkv = (c < KIN) ? Wk[c*D + h*64+d] : bk[h*64+d];
            s += qc[h*64+d]*wkv;
        }
        cF[col] = s;
    }
}

// Bcat (bf16): rows [0, 2*span) = fused Wvo rows (h*span + (c-cmin));
//              rows [2*span, 2*span+128) = Wo[D + r][j]  (bottom half of Wo)
__global__ void k_bcat(const float* Wv, const float* Wo, unsigned short* Bcat, int cmin){
    int span = KIN - cmin; int rows = 2*span;
    int r = blockIdx.x; int j = threadIdx.x;
    float a;
    if(r < rows){
        int h = r/span; int c = cmin + (r - h*span);
        a = 0.f;
        for(int d=0; d<64; ++d) a += Wv[c*D + h*64+d] * Wo[(h*64+d)*D + j];
    } else {
        a = Wo[(size_t)(D + (r - rows))*D + j];
    }
    Bcat[(size_t)r*D + j] = f2b(a);
}

// ---------- GRU memory update on M rows ----------
__global__ void k_map_init(int* map){ int i = blockIdx.x*256+threadIdx.x; if(i<NNC) map[i] = -1; }
__global__ void k_map_scatter(const int* msg_nids, int* map){
    int i = blockIdx.x*256+threadIdx.x; if(i<MC) map[msg_nids[i]] = i;
}

// 8 msgs/block, 384 threads (gate g = tid>>7 in parallel), two-phase
__global__ __launch_bounds__(384) void k_gru(const float* msgs, const float* memory, const int* msg_nids,
                      const float* Wih, const float* bih, const float* Whh, const float* bhh,
                      float* upd){
    __shared__ float xs[8*MSG];
    __shared__ float hsm[8*D];
    __shared__ float si[3*128*8];
    __shared__ float sh[3*128*8];
    int blk = blockIdx.x; int tid = threadIdx.x;
    const float* mrow = msgs + (size_t)blk*8*MSG;
    for(int i=tid; i<8*MSG; i+=384) xs[i] = mrow[i];
    for(int i=tid; i<8*D; i+=384){
        int m = i>>7; int c = i&127;
        hsm[i] = memory[(size_t)msg_nids[blk*8+m]*D + c];
    }
    __syncthreads();
    int g = tid>>7, d = tid&127;
    float ai[8], ah[8];
    #pragma unroll
    for(int m=0;m<8;++m){ ai[m]=0.f; ah[m]=0.f; }
    const float* wi = Wih + (size_t)(g*D+d)*MSG;
    for(int c=0;c<MSG;c+=4){
        float4 w4 = *(const float4*)(wi + c);
        #pragma unroll
        for(int m=0;m<8;++m){
            float4 x4 = *(const float4*)(xs + m*MSG + c);
            ai[m] += w4.x*x4.x + w4.y*x4.y + w4.z*x4.z + w4.w*x4.w;
        }
    }
    const float* wh = Whh + (size_t)(g*D+d)*D;
    for(int c=0;c<D;c+=4){
        float4 w4 = *(const float4*)(wh + c);
        #pragma unroll
        for(int m=0;m<8;++m){
            float4 h4 = *(const float4*)(hsm + m*D + c);
            ah[m] += w4.x*h4.x + w4.y*h4.y + w4.z*h4.z + w4.w*h4.w;
        }
    }
    float bi = bih[g*D+d], bh = bhh[g*D+d];
    #pragma unroll
    for(int m=0;m<8;++m){ si[tid*8+m] = ai[m]+bi; sh[tid*8+m] = ah[m]+bh; }
    __syncthreads();
    if(tid < 128){
        #pragma unroll
        for(int m=0;m<8;++m){
            float ir = si[(0*128+tid)*8+m], hr = sh[(0*128+tid)*8+m];
            float iz = si[(1*128+tid)*8+m], hz = sh[(1*128+tid)*8+m];
            float in_= si[(2*128+tid)*8+m], hn = sh[(2*128+tid)*8+m];
            float r = sigmoidf_(ir+hr);
            float u = sigmoidf_(iz+hz);
            float nn = tanhf(in_ + r*hn);
            upd[(size_t)(blk*8+m)*D + tid] = (1.f-u)*nn + u*hsm[m*D+tid];
        }
    }
}

// fused gather for both hops: writes bf16 h into hb* and into trailing cols of Acat*
__global__ void k_gatherf(const int* seed1,const int* seed0,const int* map,
                          const float* memory,const float* upd,
                          unsigned short* hb1, unsigned short* acat1,
                          unsigned short* hb0, unsigned short* acat0){
    int i = blockIdx.x*256 + threadIdx.x;
    const int total1 = N1C*D;
    int li; const int* seed; unsigned short* hb; unsigned short* acat; int ldav, hoff;
    if(i < total1){ li=i; seed=seed1; hb=hb1; acat=acat1; ldav=584; hoff=456; }
    else { li = i - total1; if(li >= N0C*D) return; seed=seed0; hb=hb0; acat=acat0; ldav=840; hoff=712; }
    int row = li>>7, c = li&127;
    int sid = seed[row];
    int mi = map[sid];
    float v = (mi>=0) ? upd[(size_t)mi*D + c] : memory[(size_t)sid*D + c];
    unsigned short u = f2b(v);
    hb[li] = u;
    acat[(size_t)row*ldav + hoff + c] = u;
}

// ---------- bf16 MFMA GEMM: C[M x N] = op(A[M x K] @ B[K x N] + bias) ----------
// BM x 64 tile, BK=64, 256 threads (4 waves), wave = BM/4 rows x 64 cols
template<int BM, bool RELU, bool OUTF32>
__global__ __launch_bounds__(256) void k_gmm(const unsigned short* A, int lda,
                                             const unsigned short* B, int ldb,
                                             const float* bias, void* Cp, int ldc,
                                             int K, int N){
    constexpr int ASTR = 72;
    constexpr int BSTR = 72;
    constexpr int RPW = BM/4;       // rows per wave
    constexpr int RT  = RPW/16;     // 16-row tiles per wave
    constexpr int AIT = BM/32;      // A staging iterations
    __shared__ unsigned short As[BM*ASTR];
    __shared__ unsigned short Bs[64*BSTR];
    int t = threadIdx.x;
    int wave = t>>6, lane = t&63;
    int l15 = lane&15, l4 = lane>>4;
    int m0 = blockIdx.y*BM, n0 = blockIdx.x*64;
    f32x4 acc[RT][4];
    #pragma unroll
    for(int rt=0;rt<RT;++rt)
        #pragma unroll
        for(int ct=0;ct<4;++ct) acc[rt][ct] = (f32x4){0.f,0.f,0.f,0.f};

    int ntiles = (K+63)>>6;
    for(int kt=0; kt<ntiles; ++kt){
        int k0 = kt<<6;
        if(kt) __syncthreads();
        #pragma unroll
        for(int i=0;i<AIT;++i){
            int idx = t + i*256;
            int row = idx>>3; int kc = (idx&7)*8;
            uint4 v = {0u,0u,0u,0u};
            if(k0+kc < K) v = *(const uint4*)(A + (size_t)(m0+row)*lda + k0 + kc);
            *(uint4*)&As[row*ASTR + kc] = v;
        }
        {
            int n = t&63; int kb = (t>>6)*16;
            int ng = n0+n;
            #pragma unroll
            for(int j=0;j<16;++j){
                int kg = k0 + kb + j;
                unsigned short v = (kg<K && ng<N) ? B[(size_t)kg*ldb + ng] : (unsigned short)0;
                Bs[n*BSTR + kb + j] = v;
            }
        }
        __syncthreads();
        #pragma unroll
        for(int kk=0; kk<64; kk+=32){
            short8v bfr[4];
            #pragma unroll
            for(int ct=0;ct<4;++ct)
                bfr[ct] = *(const short8v*)&Bs[(ct*16+l15)*BSTR + kk + l4*8];
            #pragma unroll
            for(int rt=0;rt<RT;++rt){
                short8v afr = *(const short8v*)&As[(wave*RPW + rt*16 + l15)*ASTR + kk + l4*8];
                #pragma unroll
                for(int ct=0;ct<4;++ct)
                    acc[rt][ct] = __builtin_amdgcn_mfma_f32_16x16x32_bf16(afr, bfr[ct], acc[rt][ct], 0,0,0);
            }
        }
    }
    #pragma unroll
    for(int rt=0;rt<RT;++rt){
        #pragma unroll
        for(int ct=0;ct<4;++ct){
            int col = n0 + ct*16 + l15;
            if(col < N){
                float bb = bias[col];
                #pragma unroll
                for(int r=0;r<4;++r){
                    int row = m0 + wave*RPW + rt*16 + l4*4 + r;
                    float v = acc[rt][ct][r] + bb;
                    if(RELU) v = fmaxf(v, 0.f);
                    if(OUTF32) ((float*)Cp)[(size_t)row*ldc + col] = v;
                    else ((unsigned short*)Cp)[(size_t)row*ldc + col] = f2b(v);
                }
            }
        }
    }
}

// fused scores + masked softmax + av; 4 nodes/block (one wave each), pair-mapped lanes
// qw layout: row stride QLD=2*(SPAN+2), head h at h*(SPAN+2), local col cl=c-CMIN, qb at cl=SPAN
template<int K, int CMIN, int S2>
__global__ __launch_bounds__(256) void k_attn(const unsigned short* qwb,
    unsigned short* avout, int ldav,
    const float* times, const float* nbr_times, const float* nbr_feats,
    const int* nbr_mask, const int* nbr_local, const unsigned short* zbuf,
    const float* time_w, const float* time_b){
    constexpr int SPAN = KIN - CMIN;
    constexpr int QSTR = SPAN + 2;
    constexpr int QLD  = 2*QSTR;
    int wid = threadIdx.x>>6, lane = threadIdx.x&63;
    int n = blockIdx.x*4 + wid;
    const unsigned short* qrow = qwb + (size_t)n*QLD;

    float2 qwreg[NHD][S2]; float qb[NHD];
    #pragma unroll
    for(int h=0;h<NHD;++h){
        qb[h] = b2f(qrow[h*QSTR + SPAN]);
        #pragma unroll
        for(int s=0;s<S2;++s){
            int cl = s*128 + lane*2;
            float2 v = {0.f,0.f};
            if(cl < SPAN){
                unsigned int w = *(const unsigned int*)(qrow + h*QSTR + cl);
                v.x = __uint_as_float(w<<16);
                v.y = __uint_as_float(w & 0xffff0000u);
            }
            qwreg[h][s] = v;
        }
    }
    float2 tw2[S2], tb2[S2];
    #pragma unroll
    for(int s=0;s<S2;++s){
        int c = CMIN + s*128 + lane*2;
        if(c >= D+E && c < KIN){
            tw2[s] = *(const float2*)(time_w + (c-(D+E)));
            tb2[s] = *(const float2*)(time_b + (c-(D+E)));
        } else { tw2[s]=(float2){0.f,0.f}; tb2[s]=(float2){0.f,0.f}; }
    }
    float tn = times[n];
    float2 kin2[K][S2];
    float sval[NHD][K];
    #pragma unroll
    for(int k=0;k<K;++k){
        float dt = tn - nbr_times[(size_t)n*K + k];
        const float* ef = nbr_feats + (size_t)(n*K+k)*E;
        const unsigned short* zf = (CMIN==0) ? (zbuf + (size_t)(nbr_local[(size_t)n*K+k] - N0C)*D) : (const unsigned short*)0;
        float p0=0.f, p1=0.f;
        #pragma unroll
        for(int s=0;s<S2;++s){
            int c = CMIN + s*128 + lane*2;
            float2 kv = {0.f,0.f};
            if(c < KIN){
                if(CMIN==0 && c < D){
                    unsigned int w = *(const unsigned int*)(zf + c);
                    kv.x = __uint_as_float(w<<16);
                    kv.y = __uint_as_float(w & 0xffff0000u);
                } else if(c < D+E){
                    kv = *(const float2*)(ef + (c-D));
                } else {
                    kv.x = __cosf(dt*tw2[s].x + tb2[s].x);
                    kv.y = __cosf(dt*tw2[s].y + tb2[s].y);
                }
            }
            kin2[k][s] = kv;
            p0 += kv.x*qwreg[0][s].x + kv.y*qwreg[0][s].y;
            p1 += kv.x*qwreg[1][s].x + kv.y*qwreg[1][s].y;
        }
        #pragma unroll
        for(int off=32; off; off>>=1){ p0 += __shfl_xor(p0, off); p1 += __shfl_xor(p1, off); }
        int mk = nbr_mask[(size_t)n*K + k];
        sval[0][k] = (mk>0) ? (p0 + qb[0])*0.125f : -1e9f;
        sval[1][k] = (mk>0) ? (p1 + qb[1])*0.125f : -1e9f;
    }
    float a[NHD][K];
    #pragma unroll
    for(int h=0;h<NHD;++h){
        float mx = -1e30f;
        #pragma unroll
        for(int k=0;k<K;++k) mx = fmaxf(mx, sval[h][k]);
        float z=0.f;
        #pragma unroll
        for(int k=0;k<K;++k){ float e = __expf(sval[h][k]-mx); a[h][k]=e; z+=e; }
        float inv = 1.f/z;
        #pragma unroll
        for(int k=0;k<K;++k) a[h][k]*=inv;
    }
    #pragma unroll
    for(int h=0;h<NHD;++h)
      #pragma unroll
      for(int s=0;s<S2;++s){
        int cl = s*128 + lane*2;
        if(cl < SPAN){
            float vx=0.f, vy=0.f;
            #pragma unroll
            for(int k=0;k<K;++k){ vx += a[h][k]*kin2[k][s].x; vy += a[h][k]*kin2[k][s].y; }
            unsigned int w = (unsigned int)f2b(vx) | ((unsigned int)f2b(vy)<<16);
            *(unsigned int*)(avout + (size_t)n*ldav + h*SPAN + cl) = w;
        }
      }
}

// link prediction: both (src,dst) and (src,neg) per block
__global__ __launch_bounds__(128) void k_linkpred(const float* z0,
      const int* src,const int* dst,const int* neg,
      const float* Ws,const float* bs,const float* Wd,const float* bd,
      const float* Wo,const float* bo, float* out){
    __shared__ float zs[D], zd[D], zn[D];
    __shared__ float red[4];
    int b = blockIdx.x; int d = threadIdx.x;
    zs[d] = z0[(size_t)src[b]*D + d];
    zd[d] = z0[(size_t)dst[b]*D + d];
    zn[d] = z0[(size_t)neg[b]*D + d];
    __syncthreads();
    float ss=0.f, sdd=0.f, snn=0.f;
    for(int c=0;c<D;++c){
        float w1 = Ws[c*D + d], w2 = Wd[c*D + d];
        ss  += zs[c]*w1; sdd += zd[c]*w2; snn += zn[c]*w2;
    }
    float bb = bs[d] + bd[d];
    float h1 = fmaxf(ss + sdd + bb, 0.f);
    float h2 = fmaxf(ss + snn + bb, 0.f);
    float w = Wo[d];
    float v1 = h1*w, v2 = h2*w;
    #pragma unroll
    for(int off=32; off; off>>=1){ v1 += __shfl_xor(v1,off); v2 += __shfl_xor(v2,off); }
    int wid = d>>6;
    if((d&63)==0){ red[wid*2]=v1; red[wid*2+1]=v2; }
    __syncthreads();
    if(d==0){
        out[b]       = sigmoidf_(red[0]+red[2] + bo[0]);
        out[BSZ + b] = sigmoidf_(red[1]+red[3] + bo[0]);
    }
}

extern "C" void kernel_launch(void* const* d_in, const int* in_sizes, int n_in,
                              void* d_out, int out_size, void* d_ws, size_t ws_size,
                              hipStream_t stream) {
    const float* memory  = (const float*)d_in[0];
    const float* time_w  = (const float*)d_in[1];
    const float* time_b  = (const float*)d_in[2];
    const float* gWih    = (const float*)d_in[3];
    const float* gbih    = (const float*)d_in[4];
    const float* gWhh    = (const float*)d_in[5];
    const float* gbhh    = (const float*)d_in[6];
    const float* Wq0=(const float*)d_in[7],  *bq0=(const float*)d_in[8];
    const float* Wk0=(const float*)d_in[9],  *bk0=(const float*)d_in[10];
    const float* Wv0=(const float*)d_in[11], *bv0=(const float*)d_in[12];
    const float* Wo0=(const float*)d_in[13], *bo0=(const float*)d_in[14];
    const float* Wq1=(const float*)d_in[15], *bq1=(const float*)d_in[16];
    const float* Wk1=(const float*)d_in[17], *bk1=(const float*)d_in[18];
    const float* Wv1=(const float*)d_in[19], *bv1=(const float*)d_in[20];
    const float* Wo1=(const float*)d_in[21], *bo1=(const float*)d_in[22];
    const float* lpWs=(const float*)d_in[23], *lpbs=(const float*)d_in[24];
    const float* lpWd=(const float*)d_in[25], *lpbd=(const float*)d_in[26];
    const float* lpWo=(const float*)d_in[27], *lpbo=(const float*)d_in[28];
    const float* msgs    = (const float*)d_in[29];
    const float* times0  = (const float*)d_in[30];
    const float* ntimes0 = (const float*)d_in[31];
    const float* nfeats0 = (const float*)d_in[32];
    const float* times1  = (const float*)d_in[33];
    const float* ntimes1 = (const float*)d_in[34];
    const float* nfeats1 = (const float*)d_in[35];
    const int* msg_nids  = (const int*)d_in[36];
    const int* seed0     = (const int*)d_in[37];
    const int* seed1     = (const int*)d_in[38];
    const int* nbr_local0= (const int*)d_in[39];
    const int* nbr_mask0 = (const int*)d_in[40];
    const int* nbr_mask1 = (const int*)d_in[41];
    const int* src       = (const int*)d_in[42];
    const int* dst       = (const int*)d_in[43];
    const int* neg       = (const int*)d_in[44];

    char* ws = (char*)d_ws;
    size_t off = 0;
    auto alloc = [&](size_t bytes)->char*{
        char* p = ws + off;
        off += (bytes + 255) & ~(size_t)255;
        return p;
    };
    int*   map   = (int*)  alloc((size_t)NNC*4);
    float* upd   = (float*)alloc((size_t)MC*D*4);
    unsigned short* hb1   = (unsigned short*)alloc((size_t)N1C*D*2);
    unsigned short* qwb1  = (unsigned short*)alloc((size_t)N1C*460*2);
    unsigned short* acat1 = (unsigned short*)alloc((size_t)N1C*584*2);
    unsigned short* zb1   = (unsigned short*)alloc((size_t)N1C*D*2);
    unsigned short* hb0   = (unsigned short*)alloc((size_t)N0C*D*2);
    unsigned short* qwb0  = (unsigned short*)alloc((size_t)N0C*716*2);
    unsigned short* acat0 = (unsigned short*)alloc((size_t)N0C*840*2);
    float* z0    = (float*)alloc((size_t)N0C*D*4);
    float* qc0   = (float*)alloc(512);
    float* qc1   = (float*)alloc(512);
    float* cb0   = (float*)alloc(512);
    float* cb1   = (float*)alloc(512);
    unsigned short* WFb0 = (unsigned short*)alloc((size_t)D*716*2);
    unsigned short* WFb1 = (unsigned short*)alloc((size_t)D*460*2);
    float* cF0   = (float*)alloc((size_t)716*4);
    float* cF1   = (float*)alloc((size_t)460*4);
    unsigned short* Bcat1 = (unsigned short*)alloc((size_t)584*D*2);
    unsigned short* Bcat0 = (unsigned short*)alloc((size_t)840*D*2);
    float* outp = (float*)d_out;

    // precompute
    k_pre_small<<<1,128,0,stream>>>(time_b, Wq0,bq0,Wq1,bq1, bv0,Wo0,bo0, bv1,Wo1,bo1,
                                    qc0,qc1,cb0,cb1);
    k_wf<<<2*357,128,0,stream>>>(Wq0,Wk0,bk0,qc0, WFb0,cF0, 0);     // width 716
    k_wf<<<2*229,128,0,stream>>>(Wq1,Wk1,bk1,qc1, WFb1,cF1, 128);   // width 460
    k_bcat<<<584,128,0,stream>>>(Wv1, Wo1, Bcat1, 128);   // 2*228 + 128 rows
    k_bcat<<<840,128,0,stream>>>(Wv0, Wo0, Bcat0, 0);     // 2*356 + 128 rows

    // GRU memory update
    k_map_init<<<(NNC+255)/256,256,0,stream>>>(map);
    k_map_scatter<<<MC/256,256,0,stream>>>(msg_nids, map);
    k_gru<<<MC/8,384,0,stream>>>(msgs, memory, msg_nids, gWih,gbih,gWhh,gbhh, upd);

    // gather node states (both hops, one launch) -> bf16
    k_gatherf<<<((N1C+N0C)*D)/256,256,0,stream>>>(seed1, seed0, map, memory, upd,
                                                  hb1, acat1, hb0, acat0);

    // GEMM1 (MFMA): qw = h @ WF + cF
    k_gmm<128,false,false><<<dim3(8,  N1C/128),256,0,stream>>>(hb1,128, WFb1,460, cF1, qwb1,460, 128, 460);
    k_gmm<128,false,false><<<dim3(12, N0C/128),256,0,stream>>>(hb0,128, WFb0,716, cF0, qwb0,716, 128, 716);

    // hop 1 attention -> av into acat1 cols [0,456)
    k_attn<K1C,128,2><<<N1C/4,256,0,stream>>>(qwb1, acat1, 584, times1, ntimes1, nfeats1,
                                              nbr_mask1, (const int*)0, (const unsigned short*)0,
                                              time_w, time_b);
    // GEMM2 hop1 (MFMA): z1 = relu(acat1 @ Bcat1 + cb1) -> bf16
    k_gmm<128,true,false><<<dim3(2, N1C/128),256,0,stream>>>(acat1,584, Bcat1,D, cb1, zb1,D, 584, D);

    // hop 0 attention -> av into acat0 cols [0,712)
    k_attn<K0C,0,3><<<N0C/4,256,0,stream>>>(qwb0, acat0, 840, times0, ntimes0, nfeats0,
                                            nbr_mask0, nbr_local0, zb1,
                                            time_w, time_b);
    // GEMM2 hop0 (MFMA): z0 = relu(acat0 @ Bcat0 + cb0) -> f32
    k_gmm<64,true,true><<<dim3(2, N0C/64),256,0,stream>>>(acat0,840, Bcat0,D, cb0, z0,D, 840, D);

    // link prediction
    k_linkpred<<<BSZ,128,0,stream>>>(z0, src,dst,neg, lpWs,lpbs,lpWd,lpbd, lpWo,lpbo, outp);
}

// Round 6
// 740.887 us; speedup vs baseline: 1.6863x; 1.0519x over previous
//
#include <hip/hip_runtime.h>
#include <math.h>

// ---- problem constants ----
#define D    128
#define TT   128
#define E    100
#define NHD  2
#define BSZ  2048
#define N0C  6144
#define K0C  5
#define N1C  30720
#define K1C  10
#define NNC  200000
#define MC   4096
#define MSG  484
#define KIN  356        // D+E+T
#define GK   612        // MSG + D (GRU GEMM K)
#define GKP  616        // padded to 8
#define GN   512        // GRU GEMM N (256 rz-sum + 128 in + 128 hn)

typedef __attribute__((ext_vector_type(8))) short short8v;   // 8 bf16 (4 VGPRs)
typedef __attribute__((ext_vector_type(4))) float f32x4;

__device__ __forceinline__ float sigmoidf_(float x){ return 1.f/(1.f+__expf(-x)); }
__device__ __forceinline__ unsigned short f2b(float f){
    unsigned int x = __float_as_uint(f);
    unsigned int r = (x + 0x7fffu + ((x>>16)&1u)) >> 16;
    return (unsigned short)r;
}
__device__ __forceinline__ float b2f(unsigned short u){
    return __uint_as_float(((unsigned int)u)<<16);
}

// ---------- precompute: qc (time-const query bias), cb (fused out bias) ----------
__global__ void k_pre_small(const float* time_b,
                            const float* Wq0,const float* bq0,const float* Wq1,const float* bq1,
                            const float* bv0,const float* Wo0,const float* bo0,
                            const float* bv1,const float* Wo1,const float* bo1,
                            float* qc0, float* qc1, float* cb0, float* cb1){
    __shared__ float cosb[TT];
    int j = threadIdx.x; // 128 threads
    cosb[j] = cosf(time_b[j]);
    __syncthreads();
    float a0=bq0[j], a1=bq1[j];
    for(int t=0;t<TT;++t){ a0 += cosb[t]*Wq0[(D+t)*D + j]; a1 += cosb[t]*Wq1[(D+t)*D + j]; }
    qc0[j]=a0; qc1[j]=a1;
    float c0=bo0[j], c1=bo1[j];
    for(int jp=0;jp<D;++jp){ c0 += bv0[jp]*Wo0[jp*D + j]; c1 += bv1[jp]*Wo1[jp*D + j]; }
    cb0[j]=c0; cb1[j]=c1;
}

// WF (bf16), layout per layer: head h at col h*hstr + (c-cmin), c in [cmin,356]
// (c==356 is the qb column = bk-derived); hstr = (356-cmin)+2, width = 2*hstr
__global__ void k_wf(const float* Wq,const float* Wk,const float* bk,const float* qc,
                     unsigned short* WF, float* cF, int cmin){
    int span1 = 357 - cmin;              // number of c values (incl qb col)
    int hstr  = (356 - cmin) + 2;
    int idx = blockIdx.x;
    int h = idx / span1; int cl = idx % span1;
    int c = cmin + cl;
    int col = h*hstr + cl;
    int width = 2*hstr;
    int k = threadIdx.x;
    float a = 0.f;
    for(int d=0; d<64; ++d){
        float wkv = (c < KIN) ? Wk[c*D + h*64+d] : bk[h*64+d];
        a += Wq[k*D + h*64+d] * wkv;
    }
    WF[(size_t)k*width + col] = f2b(a);
    if(k==0){
        float s=0.f;
        for(int d=0; d<64; ++d){
            float wkv = (c < KIN) ? Wk[c*D + h*64+d] : bk[h*64+d];
            s += qc[h*64+d]*wkv;
        }
        cF[col] = s;
    }
}

// Bcat (bf16): rows [0, 2*span) = fused Wvo rows (h*span + (c-cmin));
//              rows [2*span, 2*span+128) = Wo[D + r][j]  (bottom half of Wo)
__global__ void k_bcat(const float* Wv, const float* Wo, unsigned short* Bcat, int cmin){
    int span = KIN - cmin; int rows = 2*span;
    int r = blockIdx.x; int j = threadIdx.x;
    float a;
    if(r < rows){
        int h = r/span; int c = cmin + (r - h*span);
        a = 0.f;
        for(int d=0; d<64; ++d) a += Wv[c*D + h*64+d] * Wo[(h*64+d)*D + j];
    } else {
        a = Wo[(size_t)(D + (r - rows))*D + j];
    }
    Bcat[(size_t)r*D + j] = f2b(a);
}

// ---------- GRU as GEMM: precompute packed B (612 x 512 bf16) and bias (512) ----------
// cols [0,256): stacked WihT+WhhT for r,z gates -> gives (ir+hr),(iz+hz)
// cols [256,384): WihT n-gate rows (h part zero)   -> inn
// cols [384,512): WhhT n-gate rows (x part zero)   -> hn
__global__ void k_gruB(const float* Wih, const float* Whh, unsigned short* B){
    int r = blockIdx.x;            // 612
    int j = threadIdx.x;           // 512
    float v;
    if(j < 256)      v = (r < MSG) ? Wih[(size_t)j*MSG + r] : Whh[(size_t)j*D + (r-MSG)];
    else if(j < 384) v = (r < MSG) ? Wih[(size_t)j*MSG + r] : 0.f;
    else             v = (r < MSG) ? 0.f : Whh[(size_t)(j-128)*D + (r-MSG)];
    B[(size_t)r*GN + j] = f2b(v);
}
__global__ void k_gruBias(const float* bih, const float* bhh, float* bias){
    int j = threadIdx.x + blockIdx.x*256;
    if(j >= GN) return;
    float v;
    if(j < 256)      v = bih[j] + bhh[j];
    else if(j < 384) v = bih[j];
    else             v = bhh[j-128];
    bias[j] = v;
}
// build A = [msgs | mem[msg_nids]] bf16 (4096 x 616, pad zero); also f32 copy of h_prev
__global__ void k_acvt(const float* msgs, const float* memory, const int* msg_nids,
                       unsigned short* ab, float* hprevf){
    int i = blockIdx.x*256 + threadIdx.x;
    if(i >= MC*GKP) return;
    int row = i / GKP; int c = i - row*GKP;
    float v;
    if(c < MSG) v = msgs[(size_t)row*MSG + c];
    else if(c < GK){ int d = c-MSG; v = memory[(size_t)msg_nids[row]*D + d]; hprevf[row*D+d] = v; }
    else v = 0.f;
    ab[i] = f2b(v);
}
// gates: upd = (1-u)*tanh(inn + r*hn) + u*h
__global__ void k_gates(const float* g, const float* hprevf, float* upd){
    int i = blockIdx.x*256 + threadIdx.x;
    if(i >= MC*D) return;
    int row = i>>7, d = i&127;
    const float* gr = g + (size_t)row*GN;
    float r = sigmoidf_(gr[d]);
    float u = sigmoidf_(gr[128+d]);
    float n = tanhf(gr[256+d] + r*gr[384+d]);
    upd[i] = (1.f-u)*n + u*hprevf[i];
}

// ---------- node-update map ----------
__global__ void k_map_init(int* map){ int i = blockIdx.x*256+threadIdx.x; if(i<NNC) map[i] = -1; }
__global__ void k_map_scatter(const int* msg_nids, int* map){
    int i = blockIdx.x*256+threadIdx.x; if(i<MC) map[msg_nids[i]] = i;
}

// fused gather for both hops: writes bf16 h into hb* and into trailing cols of Acat*
__global__ void k_gatherf(const int* seed1,const int* seed0,const int* map,
                          const float* memory,const float* upd,
                          unsigned short* hb1, unsigned short* acat1,
                          unsigned short* hb0, unsigned short* acat0){
    int i = blockIdx.x*256 + threadIdx.x;
    const int total1 = N1C*D;
    int li; const int* seed; unsigned short* hb; unsigned short* acat; int ldav, hoff;
    if(i < total1){ li=i; seed=seed1; hb=hb1; acat=acat1; ldav=584; hoff=456; }
    else { li = i - total1; if(li >= N0C*D) return; seed=seed0; hb=hb0; acat=acat0; ldav=840; hoff=712; }
    int row = li>>7, c = li&127;
    int sid = seed[row];
    int mi = map[sid];
    float v = (mi>=0) ? upd[(size_t)mi*D + c] : memory[(size_t)sid*D + c];
    unsigned short u = f2b(v);
    hb[li] = u;
    acat[(size_t)row*ldav + hoff + c] = u;
}

// ---------- bf16 MFMA GEMM: C[M x N] = op(A[M x K] @ B[K x N] + bias) ----------
// BM x 64 tile, BK=64, 256 threads (4 waves), wave = BM/4 rows x 64 cols
template<int BM, bool RELU, bool OUTF32>
__global__ __launch_bounds__(256) void k_gmm(const unsigned short* A, int lda,
                                             const unsigned short* B, int ldb,
                                             const float* bias, void* Cp, int ldc,
                                             int K, int N){
    constexpr int ASTR = 72;
    constexpr int BSTR = 72;
    constexpr int RPW = BM/4;       // rows per wave
    constexpr int RT  = RPW/16;     // 16-row tiles per wave
    constexpr int AIT = BM/32;      // A staging iterations
    __shared__ unsigned short As[BM*ASTR];
    __shared__ unsigned short Bs[64*BSTR];
    int t = threadIdx.x;
    int wave = t>>6, lane = t&63;
    int l15 = lane&15, l4 = lane>>4;
    int m0 = blockIdx.y*BM, n0 = blockIdx.x*64;
    f32x4 acc[RT][4];
    #pragma unroll
    for(int rt=0;rt<RT;++rt)
        #pragma unroll
        for(int ct=0;ct<4;++ct) acc[rt][ct] = (f32x4){0.f,0.f,0.f,0.f};

    int ntiles = (K+63)>>6;
    for(int kt=0; kt<ntiles; ++kt){
        int k0 = kt<<6;
        if(kt) __syncthreads();
        #pragma unroll
        for(int i=0;i<AIT;++i){
            int idx = t + i*256;
            int row = idx>>3; int kc = (idx&7)*8;
            uint4 v = {0u,0u,0u,0u};
            if(k0+kc < K) v = *(const uint4*)(A + (size_t)(m0+row)*lda + k0 + kc);
            *(uint4*)&As[row*ASTR + kc] = v;
        }
        {
            int n = t&63; int kb = (t>>6)*16;
            int ng = n0+n;
            #pragma unroll
            for(int j=0;j<16;++j){
                int kg = k0 + kb + j;
                unsigned short v = (kg<K && ng<N) ? B[(size_t)kg*ldb + ng] : (unsigned short)0;
                Bs[n*BSTR + kb + j] = v;
            }
        }
        __syncthreads();
        #pragma unroll
        for(int kk=0; kk<64; kk+=32){
            short8v bfr[4];
            #pragma unroll
            for(int ct=0;ct<4;++ct)
                bfr[ct] = *(const short8v*)&Bs[(ct*16+l15)*BSTR + kk + l4*8];
            #pragma unroll
            for(int rt=0;rt<RT;++rt){
                short8v afr = *(const short8v*)&As[(wave*RPW + rt*16 + l15)*ASTR + kk + l4*8];
                #pragma unroll
                for(int ct=0;ct<4;++ct)
                    acc[rt][ct] = __builtin_amdgcn_mfma_f32_16x16x32_bf16(afr, bfr[ct], acc[rt][ct], 0,0,0);
            }
        }
    }
    #pragma unroll
    for(int rt=0;rt<RT;++rt){
        #pragma unroll
        for(int ct=0;ct<4;++ct){
            int col = n0 + ct*16 + l15;
            if(col < N){
                float bb = bias[col];
                #pragma unroll
                for(int r=0;r<4;++r){
                    int row = m0 + wave*RPW + rt*16 + l4*4 + r;
                    float v = acc[rt][ct][r] + bb;
                    if(RELU) v = fmaxf(v, 0.f);
                    if(OUTF32) ((float*)Cp)[(size_t)row*ldc + col] = v;
                    else ((unsigned short*)Cp)[(size_t)row*ldc + col] = f2b(v);
                }
            }
        }
    }
}

// fused scores + masked softmax + av; 4 nodes/block (one wave each), pair-mapped lanes
// qw layout: row stride QLD=2*(SPAN+2), head h at h*(SPAN+2), local col cl=c-CMIN, qb at cl=SPAN
template<int K, int CMIN, int S2>
__global__ __launch_bounds__(256) void k_attn(const unsigned short* qwb,
    unsigned short* avout, int ldav,
    const float* times, const float* nbr_times, const float* nbr_feats,
    const int* nbr_mask, const int* nbr_local, const unsigned short* zbuf,
    const float* time_w, const float* time_b){
    constexpr int SPAN = KIN - CMIN;
    constexpr int QSTR = SPAN + 2;
    constexpr int QLD  = 2*QSTR;
    int wid = threadIdx.x>>6, lane = threadIdx.x&63;
    int n = blockIdx.x*4 + wid;
    const unsigned short* qrow = qwb + (size_t)n*QLD;

    float2 qwreg[NHD][S2]; float qb[NHD];
    #pragma unroll
    for(int h=0;h<NHD;++h){
        qb[h] = b2f(qrow[h*QSTR + SPAN]);
        #pragma unroll
        for(int s=0;s<S2;++s){
            int cl = s*128 + lane*2;
            float2 v = {0.f,0.f};
            if(cl < SPAN){
                unsigned int w = *(const unsigned int*)(qrow + h*QSTR + cl);
                v.x = __uint_as_float(w<<16);
                v.y = __uint_as_float(w & 0xffff0000u);
            }
            qwreg[h][s] = v;
        }
    }
    float2 tw2[S2], tb2[S2];
    #pragma unroll
    for(int s=0;s<S2;++s){
        int c = CMIN + s*128 + lane*2;
        if(c >= D+E && c < KIN){
            tw2[s] = *(const float2*)(time_w + (c-(D+E)));
            tb2[s] = *(const float2*)(time_b + (c-(D+E)));
        } else { tw2[s]=(float2){0.f,0.f}; tb2[s]=(float2){0.f,0.f}; }
    }
    float tn = times[n];
    float2 kin2[K][S2];
    float sval[NHD][K];
    #pragma unroll
    for(int k=0;k<K;++k){
        float dt = tn - nbr_times[(size_t)n*K + k];
        const float* ef = nbr_feats + (size_t)(n*K+k)*E;
        const unsigned short* zf = (CMIN==0) ? (zbuf + (size_t)(nbr_local[(size_t)n*K+k] - N0C)*D) : (const unsigned short*)0;
        float p0=0.f, p1=0.f;
        #pragma unroll
        for(int s=0;s<S2;++s){
            int c = CMIN + s*128 + lane*2;
            float2 kv = {0.f,0.f};
            if(c < KIN){
                if(CMIN==0 && c < D){
                    unsigned int w = *(const unsigned int*)(zf + c);
                    kv.x = __uint_as_float(w<<16);
                    kv.y = __uint_as_float(w & 0xffff0000u);
                } else if(c < D+E){
                    kv = *(const float2*)(ef + (c-D));
                } else {
                    kv.x = __cosf(dt*tw2[s].x + tb2[s].x);
                    kv.y = __cosf(dt*tw2[s].y + tb2[s].y);
                }
            }
            kin2[k][s] = kv;
            p0 += kv.x*qwreg[0][s].x + kv.y*qwreg[0][s].y;
            p1 += kv.x*qwreg[1][s].x + kv.y*qwreg[1][s].y;
        }
        #pragma unroll
        for(int off=32; off; off>>=1){ p0 += __shfl_xor(p0, off); p1 += __shfl_xor(p1, off); }
        int mk = nbr_mask[(size_t)n*K + k];
        sval[0][k] = (mk>0) ? (p0 + qb[0])*0.125f : -1e9f;
        sval[1][k] = (mk>0) ? (p1 + qb[1])*0.125f : -1e9f;
    }
    float a[NHD][K];
    #pragma unroll
    for(int h=0;h<NHD;++h){
        float mx = -1e30f;
        #pragma unroll
        for(int k=0;k<K;++k) mx = fmaxf(mx, sval[h][k]);
        float z=0.f;
        #pragma unroll
        for(int k=0;k<K;++k){ float e = __expf(sval[h][k]-mx); a[h][k]=e; z+=e; }
        float inv = 1.f/z;
        #pragma unroll
        for(int k=0;k<K;++k) a[h][k]*=inv;
    }
    #pragma unroll
    for(int h=0;h<NHD;++h)
      #pragma unroll
      for(int s=0;s<S2;++s){
        int cl = s*128 + lane*2;
        if(cl < SPAN){
            float vx=0.f, vy=0.f;
            #pragma unroll
            for(int k=0;k<K;++k){ vx += a[h][k]*kin2[k][s].x; vy += a[h][k]*kin2[k][s].y; }
            unsigned int w = (unsigned int)f2b(vx) | ((unsigned int)f2b(vy)<<16);
            *(unsigned int*)(avout + (size_t)n*ldav + h*SPAN + cl) = w;
        }
      }
}

// link prediction: both (src,dst) and (src,neg) per block
__global__ __launch_bounds__(128) void k_linkpred(const float* z0,
      const int* src,const int* dst,const int* neg,
      const float* Ws,const float* bs,const float* Wd,const float* bd,
      const float* Wo,const float* bo, float* out){
    __shared__ float zs[D], zd[D], zn[D];
    __shared__ float red[4];
    int b = blockIdx.x; int d = threadIdx.x;
    zs[d] = z0[(size_t)src[b]*D + d];
    zd[d] = z0[(size_t)dst[b]*D + d];
    zn[d] = z0[(size_t)neg[b]*D + d];
    __syncthreads();
    float ss=0.f, sdd=0.f, snn=0.f;
    for(int c=0;c<D;++c){
        float w1 = Ws[c*D + d], w2 = Wd[c*D + d];
        ss  += zs[c]*w1; sdd += zd[c]*w2; snn += zn[c]*w2;
    }
    float bb = bs[d] + bd[d];
    float h1 = fmaxf(ss + sdd + bb, 0.f);
    float h2 = fmaxf(ss + snn + bb, 0.f);
    float w = Wo[d];
    float v1 = h1*w, v2 = h2*w;
    #pragma unroll
    for(int off=32; off; off>>=1){ v1 += __shfl_xor(v1,off); v2 += __shfl_xor(v2,off); }
    int wid = d>>6;
    if((d&63)==0){ red[wid*2]=v1; red[wid*2+1]=v2; }
    __syncthreads();
    if(d==0){
        out[b]       = sigmoidf_(red[0]+red[2] + bo[0]);
        out[BSZ + b] = sigmoidf_(red[1]+red[3] + bo[0]);
    }
}

extern "C" void kernel_launch(void* const* d_in, const int* in_sizes, int n_in,
                              void* d_out, int out_size, void* d_ws, size_t ws_size,
                              hipStream_t stream) {
    const float* memory  = (const float*)d_in[0];
    const float* time_w  = (const float*)d_in[1];
    const float* time_b  = (const float*)d_in[2];
    const float* gWih    = (const float*)d_in[3];
    const float* gbih    = (const float*)d_in[4];
    const float* gWhh    = (const float*)d_in[5];
    const float* gbhh    = (const float*)d_in[6];
    const float* Wq0=(const float*)d_in[7],  *bq0=(const float*)d_in[8];
    const float* Wk0=(const float*)d_in[9],  *bk0=(const float*)d_in[10];
    const float* Wv0=(const float*)d_in[11], *bv0=(const float*)d_in[12];
    const float* Wo0=(const float*)d_in[13], *bo0=(const float*)d_in[14];
    const float* Wq1=(const float*)d_in[15], *bq1=(const float*)d_in[16];
    const float* Wk1=(const float*)d_in[17], *bk1=(const float*)d_in[18];
    const float* Wv1=(const float*)d_in[19], *bv1=(const float*)d_in[20];
    const float* Wo1=(const float*)d_in[21], *bo1=(const float*)d_in[22];
    const float* lpWs=(const float*)d_in[23], *lpbs=(const float*)d_in[24];
    const float* lpWd=(const float*)d_in[25], *lpbd=(const float*)d_in[26];
    const float* lpWo=(const float*)d_in[27], *lpbo=(const float*)d_in[28];
    const float* msgs    = (const float*)d_in[29];
    const float* times0  = (const float*)d_in[30];
    const float* ntimes0 = (const float*)d_in[31];
    const float* nfeats0 = (const float*)d_in[32];
    const float* times1  = (const float*)d_in[33];
    const float* ntimes1 = (const float*)d_in[34];
    const float* nfeats1 = (const float*)d_in[35];
    const int* msg_nids  = (const int*)d_in[36];
    const int* seed0     = (const int*)d_in[37];
    const int* seed1     = (const int*)d_in[38];
    const int* nbr_local0= (const int*)d_in[39];
    const int* nbr_mask0 = (const int*)d_in[40];
    const int* nbr_mask1 = (const int*)d_in[41];
    const int* src       = (const int*)d_in[42];
    const int* dst       = (const int*)d_in[43];
    const int* neg       = (const int*)d_in[44];

    char* ws = (char*)d_ws;
    size_t off = 0;
    auto alloc = [&](size_t bytes)->char*{
        char* p = ws + off;
        off += (bytes + 255) & ~(size_t)255;
        return p;
    };
    int*   map   = (int*)  alloc((size_t)NNC*4);
    float* upd   = (float*)alloc((size_t)MC*D*4);
    unsigned short* hb1   = (unsigned short*)alloc((size_t)N1C*D*2);
    unsigned short* qwb1  = (unsigned short*)alloc((size_t)N1C*460*2);
    unsigned short* acat1 = (unsigned short*)alloc((size_t)N1C*584*2);
    unsigned short* zb1   = (unsigned short*)alloc((size_t)N1C*D*2);
    unsigned short* hb0   = (unsigned short*)alloc((size_t)N0C*D*2);
    unsigned short* qwb0  = (unsigned short*)alloc((size_t)N0C*716*2);
    unsigned short* acat0 = (unsigned short*)alloc((size_t)N0C*840*2);
    float* z0    = (float*)alloc((size_t)N0C*D*4);
    float* qc0   = (float*)alloc(512);
    float* qc1   = (float*)alloc(512);
    float* cb0   = (float*)alloc(512);
    float* cb1   = (float*)alloc(512);
    unsigned short* WFb0 = (unsigned short*)alloc((size_t)D*716*2);
    unsigned short* WFb1 = (unsigned short*)alloc((size_t)D*460*2);
    float* cF0   = (float*)alloc((size_t)716*4);
    float* cF1   = (float*)alloc((size_t)460*4);
    unsigned short* Bcat1 = (unsigned short*)alloc((size_t)584*D*2);
    unsigned short* Bcat0 = (unsigned short*)alloc((size_t)840*D*2);
    unsigned short* gA    = (unsigned short*)alloc((size_t)MC*GKP*2);
    unsigned short* gB    = (unsigned short*)alloc((size_t)GK*GN*2);
    float* gBias = (float*)alloc((size_t)GN*4);
    float* gbuf  = (float*)alloc((size_t)MC*GN*4);
    float* hprevf= (float*)alloc((size_t)MC*D*4);
    float* outp = (float*)d_out;

    // precompute
    k_pre_small<<<1,128,0,stream>>>(time_b, Wq0,bq0,Wq1,bq1, bv0,Wo0,bo0, bv1,Wo1,bo1,
                                    qc0,qc1,cb0,cb1);
    k_wf<<<2*357,128,0,stream>>>(Wq0,Wk0,bk0,qc0, WFb0,cF0, 0);     // width 716
    k_wf<<<2*229,128,0,stream>>>(Wq1,Wk1,bk1,qc1, WFb1,cF1, 128);   // width 460
    k_bcat<<<584,128,0,stream>>>(Wv1, Wo1, Bcat1, 128);   // 2*228 + 128 rows
    k_bcat<<<840,128,0,stream>>>(Wv0, Wo0, Bcat0, 0);     // 2*356 + 128 rows
    k_gruB<<<GK,GN,0,stream>>>(gWih, gWhh, gB);
    k_gruBias<<<2,256,0,stream>>>(gbih, gbhh, gBias);

    // GRU memory update via MFMA GEMM
    k_map_init<<<(NNC+255)/256,256,0,stream>>>(map);
    k_map_scatter<<<MC/256,256,0,stream>>>(msg_nids, map);
    k_acvt<<<(MC*GKP+255)/256,256,0,stream>>>(msgs, memory, msg_nids, gA, hprevf);
    k_gmm<128,false,true><<<dim3(GN/64, MC/128),256,0,stream>>>(gA,GKP, gB,GN, gBias, gbuf,GN, GK, GN);
    k_gates<<<(MC*D+255)/256,256,0,stream>>>(gbuf, hprevf, upd);

    // gather node states (both hops, one launch) -> bf16
    k_gatherf<<<((N1C+N0C)*D)/256,256,0,stream>>>(seed1, seed0, map, memory, upd,
                                                  hb1, acat1, hb0, acat0);

    // GEMM1 (MFMA): qw = h @ WF + cF
    k_gmm<128,false,false><<<dim3(8,  N1C/128),256,0,stream>>>(hb1,128, WFb1,460, cF1, qwb1,460, 128, 460);
    k_gmm<128,false,false><<<dim3(12, N0C/128),256,0,stream>>>(hb0,128, WFb0,716, cF0, qwb0,716, 128, 716);

    // hop 1 attention -> av into acat1 cols [0,456)
    k_attn<K1C,128,2><<<N1C/4,256,0,stream>>>(qwb1, acat1, 584, times1, ntimes1, nfeats1,
                                              nbr_mask1, (const int*)0, (const unsigned short*)0,
                                              time_w, time_b);
    // GEMM2 hop1 (MFMA): z1 = relu(acat1 @ Bcat1 + cb1) -> bf16
    k_gmm<128,true,false><<<dim3(2, N1C/128),256,0,stream>>>(acat1,584, Bcat1,D, cb1, zb1,D, 584, D);

    // hop 0 attention -> av into acat0 cols [0,712)
    k_attn<K0C,0,3><<<N0C/4,256,0,stream>>>(qwb0, acat0, 840, times0, ntimes0, nfeats0,
                                            nbr_mask0, nbr_local0, zb1,
                                            time_w, time_b);
    // GEMM2 hop0 (MFMA): z0 = relu(acat0 @ Bcat0 + cb0) -> f32
    k_gmm<64,true,true><<<dim3(2, N0C/64),256,0,stream>>>(acat0,840, Bcat0,D, cb0, z0,D, 840, D);

    // link prediction
    k_linkpred<<<BSZ,128,0,stream>>>(z0, src,dst,neg, lpWs,lpbs,lpWd,lpbd, lpWo,lpbo, outp);
}

// Round 7
// 712.813 us; speedup vs baseline: 1.7527x; 1.0394x over previous
//
#include <hip/hip_runtime.h>
#include <math.h>

// ---- problem constants ----
#define D    128
#define TT   128
#define E    100
#define NHD  2
#define BSZ  2048
#define N0C  6144
#define K0C  5
#define N1C  30720
#define K1C  10
#define NNC  200000
#define MC   4096
#define MSG  484
#define KIN  356        // D+E+T
#define GK   612        // MSG + D (GRU GEMM K)
#define GKP  616        // padded to 8
#define GN   512        // GRU GEMM N (256 rz-sum + 128 in + 128 hn)

typedef __attribute__((ext_vector_type(8))) short short8v;   // 8 bf16 (4 VGPRs)
typedef __attribute__((ext_vector_type(4))) float f32x4;

__device__ __forceinline__ float sigmoidf_(float x){ return 1.f/(1.f+__expf(-x)); }
__device__ __forceinline__ unsigned short f2b(float f){
    unsigned int x = __float_as_uint(f);
    unsigned int r = (x + 0x7fffu + ((x>>16)&1u)) >> 16;
    return (unsigned short)r;
}
__device__ __forceinline__ float b2f(unsigned short u){
    return __uint_as_float(((unsigned int)u)<<16);
}

// ---------- precompute: qc (time-const query bias), cb (fused out bias) ----------
__global__ void k_pre_small(const float* time_b,
                            const float* Wq0,const float* bq0,const float* Wq1,const float* bq1,
                            const float* bv0,const float* Wo0,const float* bo0,
                            const float* bv1,const float* Wo1,const float* bo1,
                            float* qc0, float* qc1, float* cb0, float* cb1){
    __shared__ float cosb[TT];
    int j = threadIdx.x; // 128 threads
    cosb[j] = cosf(time_b[j]);
    __syncthreads();
    float a0=bq0[j], a1=bq1[j];
    for(int t=0;t<TT;++t){ a0 += cosb[t]*Wq0[(D+t)*D + j]; a1 += cosb[t]*Wq1[(D+t)*D + j]; }
    qc0[j]=a0; qc1[j]=a1;
    float c0=bo0[j], c1=bo1[j];
    for(int jp=0;jp<D;++jp){ c0 += bv0[jp]*Wo0[jp*D + j]; c1 += bv1[jp]*Wo1[jp*D + j]; }
    cb0[j]=c0; cb1[j]=c1;
}

// WF (bf16), head h at col h*hstr + cl, cl in [0,span] (cl==span is qb col = bk-derived)
// hstr = span + 4 (pad cols zeroed); width = 2*hstr
__global__ void k_wf(const float* Wq,const float* Wk,const float* bk,const float* qc,
                     unsigned short* WF, float* cF, int cmin){
    int span = 356 - cmin;
    int hstr = span + 4;
    int width = 2*hstr;
    int idx = blockIdx.x;            // [0, 2*hstr)
    int h = idx / hstr; int cl = idx % hstr;
    int k = threadIdx.x;
    if(cl > span){
        WF[(size_t)k*width + idx] = (unsigned short)0;
        if(k==0) cF[idx] = 0.f;
        return;
    }
    int c = cmin + cl;
    float a = 0.f;
    for(int d=0; d<64; ++d){
        float wkv = (c < KIN) ? Wk[c*D + h*64+d] : bk[h*64+d];
        a += Wq[k*D + h*64+d] * wkv;
    }
    WF[(size_t)k*width + idx] = f2b(a);
    if(k==0){
        float s=0.f;
        for(int d=0; d<64; ++d){
            float wkv = (c < KIN) ? Wk[c*D + h*64+d] : bk[h*64+d];
            s += qc[h*64+d]*wkv;
        }
        cF[idx] = s;
    }
}

// Bcat (bf16): rows [0, 2*span) = fused Wvo rows (h*span + (c-cmin));
//              rows [2*span, 2*span+128) = Wo[D + r][j]  (bottom half of Wo)
__global__ void k_bcat(const float* Wv, const float* Wo, unsigned short* Bcat, int cmin){
    int span = KIN - cmin; int rows = 2*span;
    int r = blockIdx.x; int j = threadIdx.x;
    float a;
    if(r < rows){
        int h = r/span; int c = cmin + (r - h*span);
        a = 0.f;
        for(int d=0; d<64; ++d) a += Wv[c*D + h*64+d] * Wo[(h*64+d)*D + j];
    } else {
        a = Wo[(size_t)(D + (r - rows))*D + j];
    }
    Bcat[(size_t)r*D + j] = f2b(a);
}

// ---------- GRU as GEMM: packed B (612 x 512 bf16) and bias (512) ----------
__global__ void k_gruB(const float* Wih, const float* Whh, unsigned short* B){
    int r = blockIdx.x;            // 612
    int j = threadIdx.x;           // 512
    float v;
    if(j < 256)      v = (r < MSG) ? Wih[(size_t)j*MSG + r] : Whh[(size_t)j*D + (r-MSG)];
    else if(j < 384) v = (r < MSG) ? Wih[(size_t)j*MSG + r] : 0.f;
    else             v = (r < MSG) ? 0.f : Whh[(size_t)(j-128)*D + (r-MSG)];
    B[(size_t)r*GN + j] = f2b(v);
}
__global__ void k_gruBias(const float* bih, const float* bhh, float* bias){
    int j = threadIdx.x + blockIdx.x*256;
    if(j >= GN) return;
    float v;
    if(j < 256)      v = bih[j] + bhh[j];
    else if(j < 384) v = bih[j];
    else             v = bhh[j-128];
    bias[j] = v;
}
__global__ void k_acvt(const float* msgs, const float* memory, const int* msg_nids,
                       unsigned short* ab, float* hprevf){
    int i = blockIdx.x*256 + threadIdx.x;
    if(i >= MC*GKP) return;
    int row = i / GKP; int c = i - row*GKP;
    float v;
    if(c < MSG) v = msgs[(size_t)row*MSG + c];
    else if(c < GK){ int d = c-MSG; v = memory[(size_t)msg_nids[row]*D + d]; hprevf[row*D+d] = v; }
    else v = 0.f;
    ab[i] = f2b(v);
}
__global__ void k_gates(const float* g, const float* hprevf, float* upd){
    int i = blockIdx.x*256 + threadIdx.x;
    if(i >= MC*D) return;
    int row = i>>7, d = i&127;
    const float* gr = g + (size_t)row*GN;
    float r = sigmoidf_(gr[d]);
    float u = sigmoidf_(gr[128+d]);
    float n = tanhf(gr[256+d] + r*gr[384+d]);
    upd[i] = (1.f-u)*n + u*hprevf[i];
}

// ---------- node-update map ----------
__global__ void k_map_init(int* map){ int i = blockIdx.x*256+threadIdx.x; if(i<NNC) map[i] = -1; }
__global__ void k_map_scatter(const int* msg_nids, int* map){
    int i = blockIdx.x*256+threadIdx.x; if(i<MC) map[msg_nids[i]] = i;
}

// fused gather for both hops: writes bf16 h into hb* and into trailing cols of Acat*
__global__ void k_gatherf(const int* seed1,const int* seed0,const int* map,
                          const float* memory,const float* upd,
                          unsigned short* hb1, unsigned short* acat1,
                          unsigned short* hb0, unsigned short* acat0){
    int i = blockIdx.x*256 + threadIdx.x;
    const int total1 = N1C*D;
    int li; const int* seed; unsigned short* hb; unsigned short* acat; int ldav, hoff;
    if(i < total1){ li=i; seed=seed1; hb=hb1; acat=acat1; ldav=584; hoff=456; }
    else { li = i - total1; if(li >= N0C*D) return; seed=seed0; hb=hb0; acat=acat0; ldav=840; hoff=712; }
    int row = li>>7, c = li&127;
    int sid = seed[row];
    int mi = map[sid];
    float v = (mi>=0) ? upd[(size_t)mi*D + c] : memory[(size_t)sid*D + c];
    unsigned short u = f2b(v);
    hb[li] = u;
    acat[(size_t)row*ldav + hoff + c] = u;
}

// ---------- bf16 MFMA GEMM: C[M x N] = op(A[M x K] @ B[K x N] + bias) ----------
template<int BM, bool RELU, bool OUTF32>
__global__ __launch_bounds__(256) void k_gmm(const unsigned short* A, int lda,
                                             const unsigned short* B, int ldb,
                                             const float* bias, void* Cp, int ldc,
                                             int K, int N){
    constexpr int ASTR = 72;
    constexpr int BSTR = 72;
    constexpr int RPW = BM/4;       // rows per wave
    constexpr int RT  = RPW/16;     // 16-row tiles per wave
    constexpr int AIT = BM/32;      // A staging iterations
    __shared__ unsigned short As[BM*ASTR];
    __shared__ unsigned short Bs[64*BSTR];
    int t = threadIdx.x;
    int wave = t>>6, lane = t&63;
    int l15 = lane&15, l4 = lane>>4;
    int m0 = blockIdx.y*BM, n0 = blockIdx.x*64;
    f32x4 acc[RT][4];
    #pragma unroll
    for(int rt=0;rt<RT;++rt)
        #pragma unroll
        for(int ct=0;ct<4;++ct) acc[rt][ct] = (f32x4){0.f,0.f,0.f,0.f};

    int ntiles = (K+63)>>6;
    for(int kt=0; kt<ntiles; ++kt){
        int k0 = kt<<6;
        if(kt) __syncthreads();
        #pragma unroll
        for(int i=0;i<AIT;++i){
            int idx = t + i*256;
            int row = idx>>3; int kc = (idx&7)*8;
            uint4 v = {0u,0u,0u,0u};
            if(k0+kc < K) v = *(const uint4*)(A + (size_t)(m0+row)*lda + k0 + kc);
            *(uint4*)&As[row*ASTR + kc] = v;
        }
        {
            int n = t&63; int kb = (t>>6)*16;
            int ng = n0+n;
            #pragma unroll
            for(int j=0;j<16;++j){
                int kg = k0 + kb + j;
                unsigned short v = (kg<K && ng<N) ? B[(size_t)kg*ldb + ng] : (unsigned short)0;
                Bs[n*BSTR + kb + j] = v;
            }
        }
        __syncthreads();
        #pragma unroll
        for(int kk=0; kk<64; kk+=32){
            short8v bfr[4];
            #pragma unroll
            for(int ct=0;ct<4;++ct)
                bfr[ct] = *(const short8v*)&Bs[(ct*16+l15)*BSTR + kk + l4*8];
            #pragma unroll
            for(int rt=0;rt<RT;++rt){
                short8v afr = *(const short8v*)&As[(wave*RPW + rt*16 + l15)*ASTR + kk + l4*8];
                #pragma unroll
                for(int ct=0;ct<4;++ct)
                    acc[rt][ct] = __builtin_amdgcn_mfma_f32_16x16x32_bf16(afr, bfr[ct], acc[rt][ct], 0,0,0);
            }
        }
    }
    #pragma unroll
    for(int rt=0;rt<RT;++rt){
        #pragma unroll
        for(int ct=0;ct<4;++ct){
            int col = n0 + ct*16 + l15;
            if(col < N){
                float bb = bias[col];
                #pragma unroll
                for(int r=0;r<4;++r){
                    int row = m0 + wave*RPW + rt*16 + l4*4 + r;
                    float v = acc[rt][ct][r] + bb;
                    if(RELU) v = fmaxf(v, 0.f);
                    if(OUTF32) ((float*)Cp)[(size_t)row*ldc + col] = v;
                    else ((unsigned short*)Cp)[(size_t)row*ldc + col] = f2b(v);
                }
            }
        }
    }
}

// fused scores + masked softmax + av
// quad-lane mapping: c = CMIN + s*256 + lane*4 (all region boundaries %4==0)
// mask==0 neighbors skipped entirely (wave-uniform branch; exact: a_k would be 0)
// each wave handles NPW nodes serially; time_w/time_b hoisted per wave
// qw layout: head stride QSTR=SPAN+4, qb at cl==SPAN, row stride QLD=2*QSTR
template<int K, int CMIN, int S4, int NPW>
__global__ __launch_bounds__(256,4) void k_attn(const unsigned short* qwb,
    unsigned short* avout, int ldav,
    const float* times, const float* nbr_times, const float* nbr_feats,
    const int* nbr_mask, const int* nbr_local, const unsigned short* zbuf,
    const float* time_w, const float* time_b){
    constexpr int SPAN = KIN - CMIN;
    constexpr int QSTR = SPAN + 4;
    constexpr int QLD  = 2*QSTR;
    int wv = blockIdx.x*4 + (threadIdx.x>>6);
    int lane = threadIdx.x & 63;

    // hoisted time features (float4 per segment)
    float4 tw4[S4], tb4[S4];
    #pragma unroll
    for(int s=0;s<S4;++s){
        int c = CMIN + s*256 + lane*4;
        if(c >= D+E && c < KIN){
            tw4[s] = *(const float4*)(time_w + (c-(D+E)));
            tb4[s] = *(const float4*)(time_b + (c-(D+E)));
        } else {
            tw4[s] = make_float4(0.f,0.f,0.f,0.f);
            tb4[s] = make_float4(0.f,0.f,0.f,0.f);
        }
    }

    for(int i=0;i<NPW;++i){
        int n = wv*NPW + i;
        const unsigned short* qrow = qwb + (size_t)n*QLD;
        // per-node uniform data via lane-parallel loads + shfl
        float tval = (lane<K) ? nbr_times[(size_t)n*K + lane] : 0.f;
        int   mval = (lane<K) ? nbr_mask [(size_t)n*K + lane] : 0;
        int   nlv  = (CMIN==0 && lane<K) ? nbr_local[(size_t)n*K + lane] : 0;
        float tn = times[n];

        float4 qw4[NHD][S4]; float qb[NHD];
        #pragma unroll
        for(int h=0;h<NHD;++h){
            qb[h] = b2f(qrow[h*QSTR + SPAN]);
            #pragma unroll
            for(int s=0;s<S4;++s){
                int cl = s*256 + lane*4;
                float4 v = make_float4(0.f,0.f,0.f,0.f);
                if(cl < SPAN){
                    uint2 w = *(const uint2*)(qrow + h*QSTR + cl);
                    v.x = __uint_as_float(w.x<<16);
                    v.y = __uint_as_float(w.x & 0xffff0000u);
                    v.z = __uint_as_float(w.y<<16);
                    v.w = __uint_as_float(w.y & 0xffff0000u);
                }
                qw4[h][s] = v;
            }
        }

        float4 kin4[K][S4];
        float sval[NHD][K];
        #pragma unroll
        for(int k=0;k<K;++k){
            int mk = __shfl(mval, k);
            if(mk > 0){
                float dt = tn - __shfl(tval, k);
                const float* ef = nbr_feats + (size_t)(n*K+k)*E;
                const unsigned short* zf = (CMIN==0) ?
                    (zbuf + (size_t)(__shfl(nlv,k) - N0C)*D) : (const unsigned short*)0;
                float p0=0.f, p1=0.f;
                #pragma unroll
                for(int s=0;s<S4;++s){
                    int c = CMIN + s*256 + lane*4;
                    float4 kv = make_float4(0.f,0.f,0.f,0.f);
                    if(c < KIN){
                        if(CMIN==0 && c < D){
                            uint2 w = *(const uint2*)(zf + c);
                            kv.x = __uint_as_float(w.x<<16);
                            kv.y = __uint_as_float(w.x & 0xffff0000u);
                            kv.z = __uint_as_float(w.y<<16);
                            kv.w = __uint_as_float(w.y & 0xffff0000u);
                        } else if(c < D+E){
                            kv = *(const float4*)(ef + (c-D));
                        } else {
                            kv.x = __cosf(dt*tw4[s].x + tb4[s].x);
                            kv.y = __cosf(dt*tw4[s].y + tb4[s].y);
                            kv.z = __cosf(dt*tw4[s].z + tb4[s].z);
                            kv.w = __cosf(dt*tw4[s].w + tb4[s].w);
                        }
                    }
                    kin4[k][s] = kv;
                    p0 += kv.x*qw4[0][s].x + kv.y*qw4[0][s].y + kv.z*qw4[0][s].z + kv.w*qw4[0][s].w;
                    p1 += kv.x*qw4[1][s].x + kv.y*qw4[1][s].y + kv.z*qw4[1][s].z + kv.w*qw4[1][s].w;
                }
                #pragma unroll
                for(int off=32; off; off>>=1){ p0 += __shfl_xor(p0, off); p1 += __shfl_xor(p1, off); }
                sval[0][k] = (p0 + qb[0])*0.125f;
                sval[1][k] = (p1 + qb[1])*0.125f;
            } else {
                #pragma unroll
                for(int s=0;s<S4;++s) kin4[k][s] = make_float4(0.f,0.f,0.f,0.f);
                sval[0][k] = -1e9f;
                sval[1][k] = -1e9f;
            }
        }
        // softmax (in place over sval)
        #pragma unroll
        for(int h=0;h<NHD;++h){
            float mx = -1e30f;
            #pragma unroll
            for(int k=0;k<K;++k) mx = fmaxf(mx, sval[h][k]);
            float z=0.f;
            #pragma unroll
            for(int k=0;k<K;++k){ float e = __expf(sval[h][k]-mx); sval[h][k]=e; z+=e; }
            float inv = 1.f/z;
            #pragma unroll
            for(int k=0;k<K;++k) sval[h][k]*=inv;
        }
        // av (quad) -> packed bf16 store
        #pragma unroll
        for(int h=0;h<NHD;++h)
          #pragma unroll
          for(int s=0;s<S4;++s){
            int cl = s*256 + lane*4;
            if(cl < SPAN){
                float v0=0.f,v1=0.f,v2=0.f,v3=0.f;
                #pragma unroll
                for(int k=0;k<K;++k){
                    float a = sval[h][k];
                    v0 += a*kin4[k][s].x; v1 += a*kin4[k][s].y;
                    v2 += a*kin4[k][s].z; v3 += a*kin4[k][s].w;
                }
                uint2 o;
                o.x = (unsigned int)f2b(v0) | ((unsigned int)f2b(v1)<<16);
                o.y = (unsigned int)f2b(v2) | ((unsigned int)f2b(v3)<<16);
                *(uint2*)(avout + (size_t)n*ldav + h*SPAN + cl) = o;
            }
          }
    }
}

// link prediction: both (src,dst) and (src,neg) per block
__global__ __launch_bounds__(128) void k_linkpred(const float* z0,
      const int* src,const int* dst,const int* neg,
      const float* Ws,const float* bs,const float* Wd,const float* bd,
      const float* Wo,const float* bo, float* out){
    __shared__ float zs[D], zd[D], zn[D];
    __shared__ float red[4];
    int b = blockIdx.x; int d = threadIdx.x;
    zs[d] = z0[(size_t)src[b]*D + d];
    zd[d] = z0[(size_t)dst[b]*D + d];
    zn[d] = z0[(size_t)neg[b]*D + d];
    __syncthreads();
    float ss=0.f, sdd=0.f, snn=0.f;
    for(int c=0;c<D;++c){
        float w1 = Ws[c*D + d], w2 = Wd[c*D + d];
        ss  += zs[c]*w1; sdd += zd[c]*w2; snn += zn[c]*w2;
    }
    float bb = bs[d] + bd[d];
    float h1 = fmaxf(ss + sdd + bb, 0.f);
    float h2 = fmaxf(ss + snn + bb, 0.f);
    float w = Wo[d];
    float v1 = h1*w, v2 = h2*w;
    #pragma unroll
    for(int off=32; off; off>>=1){ v1 += __shfl_xor(v1,off); v2 += __shfl_xor(v2,off); }
    int wid = d>>6;
    if((d&63)==0){ red[wid*2]=v1; red[wid*2+1]=v2; }
    __syncthreads();
    if(d==0){
        out[b]       = sigmoidf_(red[0]+red[2] + bo[0]);
        out[BSZ + b] = sigmoidf_(red[1]+red[3] + bo[0]);
    }
}

extern "C" void kernel_launch(void* const* d_in, const int* in_sizes, int n_in,
                              void* d_out, int out_size, void* d_ws, size_t ws_size,
                              hipStream_t stream) {
    const float* memory  = (const float*)d_in[0];
    const float* time_w  = (const float*)d_in[1];
    const float* time_b  = (const float*)d_in[2];
    const float* gWih    = (const float*)d_in[3];
    const float* gbih    = (const float*)d_in[4];
    const float* gWhh    = (const float*)d_in[5];
    const float* gbhh    = (const float*)d_in[6];
    const float* Wq0=(const float*)d_in[7],  *bq0=(const float*)d_in[8];
    const float* Wk0=(const float*)d_in[9],  *bk0=(const float*)d_in[10];
    const float* Wv0=(const float*)d_in[11], *bv0=(const float*)d_in[12];
    const float* Wo0=(const float*)d_in[13], *bo0=(const float*)d_in[14];
    const float* Wq1=(const float*)d_in[15], *bq1=(const float*)d_in[16];
    const float* Wk1=(const float*)d_in[17], *bk1=(const float*)d_in[18];
    const float* Wv1=(const float*)d_in[19], *bv1=(const float*)d_in[20];
    const float* Wo1=(const float*)d_in[21], *bo1=(const float*)d_in[22];
    const float* lpWs=(const float*)d_in[23], *lpbs=(const float*)d_in[24];
    const float* lpWd=(const float*)d_in[25], *lpbd=(const float*)d_in[26];
    const float* lpWo=(const float*)d_in[27], *lpbo=(const float*)d_in[28];
    const float* msgs    = (const float*)d_in[29];
    const float* times0  = (const float*)d_in[30];
    const float* ntimes0 = (const float*)d_in[31];
    const float* nfeats0 = (const float*)d_in[32];
    const float* times1  = (const float*)d_in[33];
    const float* ntimes1 = (const float*)d_in[34];
    const float* nfeats1 = (const float*)d_in[35];
    const int* msg_nids  = (const int*)d_in[36];
    const int* seed0     = (const int*)d_in[37];
    const int* seed1     = (const int*)d_in[38];
    const int* nbr_local0= (const int*)d_in[39];
    const int* nbr_mask0 = (const int*)d_in[40];
    const int* nbr_mask1 = (const int*)d_in[41];
    const int* src       = (const int*)d_in[42];
    const int* dst       = (const int*)d_in[43];
    const int* neg       = (const int*)d_in[44];

    char* ws = (char*)d_ws;
    size_t off = 0;
    auto alloc = [&](size_t bytes)->char*{
        char* p = ws + off;
        off += (bytes + 255) & ~(size_t)255;
        return p;
    };
    int*   map   = (int*)  alloc((size_t)NNC*4);
    float* upd   = (float*)alloc((size_t)MC*D*4);
    unsigned short* hb1   = (unsigned short*)alloc((size_t)N1C*D*2);
    unsigned short* qwb1  = (unsigned short*)alloc((size_t)N1C*464*2);
    unsigned short* acat1 = (unsigned short*)alloc((size_t)N1C*584*2);
    unsigned short* zb1   = (unsigned short*)alloc((size_t)N1C*D*2);
    unsigned short* hb0   = (unsigned short*)alloc((size_t)N0C*D*2);
    unsigned short* qwb0  = (unsigned short*)alloc((size_t)N0C*720*2);
    unsigned short* acat0 = (unsigned short*)alloc((size_t)N0C*840*2);
    float* z0    = (float*)alloc((size_t)N0C*D*4);
    float* qc0   = (float*)alloc(512);
    float* qc1   = (float*)alloc(512);
    float* cb0   = (float*)alloc(512);
    float* cb1   = (float*)alloc(512);
    unsigned short* WFb0 = (unsigned short*)alloc((size_t)D*720*2);
    unsigned short* WFb1 = (unsigned short*)alloc((size_t)D*464*2);
    float* cF0   = (float*)alloc((size_t)720*4);
    float* cF1   = (float*)alloc((size_t)464*4);
    unsigned short* Bcat1 = (unsigned short*)alloc((size_t)584*D*2);
    unsigned short* Bcat0 = (unsigned short*)alloc((size_t)840*D*2);
    unsigned short* gA    = (unsigned short*)alloc((size_t)MC*GKP*2);
    unsigned short* gB    = (unsigned short*)alloc((size_t)GK*GN*2);
    float* gBias = (float*)alloc((size_t)GN*4);
    float* gbuf  = (float*)alloc((size_t)MC*GN*4);
    float* hprevf= (float*)alloc((size_t)MC*D*4);
    float* outp = (float*)d_out;

    // precompute
    k_pre_small<<<1,128,0,stream>>>(time_b, Wq0,bq0,Wq1,bq1, bv0,Wo0,bo0, bv1,Wo1,bo1,
                                    qc0,qc1,cb0,cb1);
    k_wf<<<720,128,0,stream>>>(Wq0,Wk0,bk0,qc0, WFb0,cF0, 0);     // width 720
    k_wf<<<464,128,0,stream>>>(Wq1,Wk1,bk1,qc1, WFb1,cF1, 128);   // width 464
    k_bcat<<<584,128,0,stream>>>(Wv1, Wo1, Bcat1, 128);   // 2*228 + 128 rows
    k_bcat<<<840,128,0,stream>>>(Wv0, Wo0, Bcat0, 0);     // 2*356 + 128 rows
    k_gruB<<<GK,GN,0,stream>>>(gWih, gWhh, gB);
    k_gruBias<<<2,256,0,stream>>>(gbih, gbhh, gBias);

    // GRU memory update via MFMA GEMM
    k_map_init<<<(NNC+255)/256,256,0,stream>>>(map);
    k_map_scatter<<<MC/256,256,0,stream>>>(msg_nids, map);
    k_acvt<<<(MC*GKP+255)/256,256,0,stream>>>(msgs, memory, msg_nids, gA, hprevf);
    k_gmm<128,false,true><<<dim3(GN/64, MC/128),256,0,stream>>>(gA,GKP, gB,GN, gBias, gbuf,GN, GK, GN);
    k_gates<<<(MC*D+255)/256,256,0,stream>>>(gbuf, hprevf, upd);

    // gather node states (both hops, one launch) -> bf16
    k_gatherf<<<((N1C+N0C)*D)/256,256,0,stream>>>(seed1, seed0, map, memory, upd,
                                                  hb1, acat1, hb0, acat0);

    // GEMM1 (MFMA): qw = h @ WF + cF
    k_gmm<128,false,false><<<dim3(8,  N1C/128),256,0,stream>>>(hb1,128, WFb1,464, cF1, qwb1,464, 128, 464);
    k_gmm<128,false,false><<<dim3(12, N0C/128),256,0,stream>>>(hb0,128, WFb0,720, cF0, qwb0,720, 128, 720);

    // hop 1 attention -> av into acat1 cols [0,456); NPW=4 -> 1920 blocks
    k_attn<K1C,128,1,4><<<N1C/16,256,0,stream>>>(qwb1, acat1, 584, times1, ntimes1, nfeats1,
                                                 nbr_mask1, (const int*)0, (const unsigned short*)0,
                                                 time_w, time_b);
    // GEMM2 hop1 (MFMA): z1 = relu(acat1 @ Bcat1 + cb1) -> bf16
    k_gmm<128,true,false><<<dim3(2, N1C/128),256,0,stream>>>(acat1,584, Bcat1,D, cb1, zb1,D, 584, D);

    // hop 0 attention -> av into acat0 cols [0,712); NPW=2 -> 768 blocks
    k_attn<K0C,0,2,2><<<N0C/8,256,0,stream>>>(qwb0, acat0, 840, times0, ntimes0, nfeats0,
                                              nbr_mask0, nbr_local0, zb1,
                                              time_w, time_b);
    // GEMM2 hop0 (MFMA): z0 = relu(acat0 @ Bcat0 + cb0) -> f32
    k_gmm<64,true,true><<<dim3(2, N0C/64),256,0,stream>>>(acat0,840, Bcat0,D, cb0, z0,D, 840, D);

    // link prediction
    k_linkpred<<<BSZ,128,0,stream>>>(z0, src,dst,neg, lpWs,lpbs,lpWd,lpbd, lpWo,lpbo, outp);
}

// Round 8
// 599.277 us; speedup vs baseline: 2.0848x; 1.1895x over previous
//
#include <hip/hip_runtime.h>
#include <math.h>

// ---- problem constants ----
#define D    128
#define TT   128
#define E    100
#define NHD  2
#define BSZ  2048
#define N0C  6144
#define K0C  5
#define N1C  30720
#define K1C  10
#define NNC  200000
#define MC   4096
#define MSG  484
#define KIN  356        // D+E+T
#define GK   612        // MSG + D (GRU GEMM K)
#define GKP  616        // padded to 8
#define GN   512        // GRU GEMM N (256 rz-sum + 128 in + 128 hn)

typedef __attribute__((ext_vector_type(8))) short short8v;   // 8 bf16 (4 VGPRs)
typedef __attribute__((ext_vector_type(4))) float f32x4;

__device__ __forceinline__ float sigmoidf_(float x){ return 1.f/(1.f+__expf(-x)); }
__device__ __forceinline__ unsigned short f2b(float f){
    unsigned int x = __float_as_uint(f);
    unsigned int r = (x + 0x7fffu + ((x>>16)&1u)) >> 16;
    return (unsigned short)r;
}
__device__ __forceinline__ float b2f(unsigned short u){
    return __uint_as_float(((unsigned int)u)<<16);
}

// ---------- precompute: qc (time-const query bias), cb (fused out bias) ----------
__global__ void k_pre_small(const float* time_b,
                            const float* Wq0,const float* bq0,const float* Wq1,const float* bq1,
                            const float* bv0,const float* Wo0,const float* bo0,
                            const float* bv1,const float* Wo1,const float* bo1,
                            float* qc0, float* qc1, float* cb0, float* cb1){
    __shared__ float cosb[TT];
    int j = threadIdx.x; // 128 threads
    cosb[j] = cosf(time_b[j]);
    __syncthreads();
    float a0=bq0[j], a1=bq1[j];
    for(int t=0;t<TT;++t){ a0 += cosb[t]*Wq0[(D+t)*D + j]; a1 += cosb[t]*Wq1[(D+t)*D + j]; }
    qc0[j]=a0; qc1[j]=a1;
    float c0=bo0[j], c1=bo1[j];
    for(int jp=0;jp<D;++jp){ c0 += bv0[jp]*Wo0[jp*D + j]; c1 += bv1[jp]*Wo1[jp*D + j]; }
    cb0[j]=c0; cb1[j]=c1;
}

// WF (bf16), head h at col h*hstr + cl, cl in [0,span] (cl==span is qb col = bk-derived)
// hstr = span + 4 (pad cols zeroed); width = 2*hstr
__global__ void k_wf(const float* Wq,const float* Wk,const float* bk,const float* qc,
                     unsigned short* WF, float* cF, int cmin){
    int span = 356 - cmin;
    int hstr = span + 4;
    int width = 2*hstr;
    int idx = blockIdx.x;            // [0, 2*hstr)
    int h = idx / hstr; int cl = idx % hstr;
    int k = threadIdx.x;
    if(cl > span){
        WF[(size_t)k*width + idx] = (unsigned short)0;
        if(k==0) cF[idx] = 0.f;
        return;
    }
    int c = cmin + cl;
    float a = 0.f;
    for(int d=0; d<64; ++d){
        float wkv = (c < KIN) ? Wk[c*D + h*64+d] : bk[h*64+d];
        a += Wq[k*D + h*64+d] * wkv;
    }
    WF[(size_t)k*width + idx] = f2b(a);
    if(k==0){
        float s=0.f;
        for(int d=0; d<64; ++d){
            float wkv = (c < KIN) ? Wk[c*D + h*64+d] : bk[h*64+d];
            s += qc[h*64+d]*wkv;
        }
        cF[idx] = s;
    }
}

// Bcat (bf16): rows [0, 2*span) = fused Wvo rows; rows [2*span, +128) = Wo bottom half
__global__ void k_bcat(const float* Wv, const float* Wo, unsigned short* Bcat, int cmin){
    int span = KIN - cmin; int rows = 2*span;
    int r = blockIdx.x; int j = threadIdx.x;
    float a;
    if(r < rows){
        int h = r/span; int c = cmin + (r - h*span);
        a = 0.f;
        for(int d=0; d<64; ++d) a += Wv[c*D + h*64+d] * Wo[(h*64+d)*D + j];
    } else {
        a = Wo[(size_t)(D + (r - rows))*D + j];
    }
    Bcat[(size_t)r*D + j] = f2b(a);
}

// ---------- GRU as GEMM: packed B (612 x 512 bf16) via coalesced LDS transpose ----------
__global__ __launch_bounds__(256) void k_gruB(const float* Wih, const float* Whh, unsigned short* B){
    __shared__ float tile[64][65];
    int rb = blockIdx.x*64;
    int jb = blockIdx.y*64;
    int t = threadIdx.x;
    int rr = t&63, jj0 = t>>6;
    #pragma unroll
    for(int i=0;i<16;++i){
        int jj = jj0 + i*4;
        int j = jb + jj; int r = rb + rr;
        float v = 0.f;
        if(r < GK){
            if(j < 256)      v = (r<MSG)? Wih[(size_t)j*MSG+r] : Whh[(size_t)j*D + (r-MSG)];
            else if(j < 384) v = (r<MSG)? Wih[(size_t)j*MSG+r] : 0.f;
            else             v = (r<MSG)? 0.f : Whh[(size_t)(j-128)*D + (r-MSG)];
        }
        tile[jj][rr] = v;
    }
    __syncthreads();
    int jw = t&63, rr0 = t>>6;
    #pragma unroll
    for(int i=0;i<16;++i){
        int rr2 = rr0 + i*4;
        int r = rb + rr2;
        if(r < GK) B[(size_t)r*GN + jb + jw] = f2b(tile[jw][rr2]);
    }
}
__global__ void k_gruBias(const float* bih, const float* bhh, float* bias){
    int j = threadIdx.x + blockIdx.x*256;
    if(j >= GN) return;
    float v;
    if(j < 256)      v = bih[j] + bhh[j];
    else if(j < 384) v = bih[j];
    else             v = bhh[j-128];
    bias[j] = v;
}
__global__ void k_acvt(const float* msgs, const float* memory, const int* msg_nids,
                       unsigned short* ab, float* hprevf){
    int i = blockIdx.x*256 + threadIdx.x;
    if(i >= MC*GKP) return;
    int row = i / GKP; int c = i - row*GKP;
    float v;
    if(c < MSG) v = msgs[(size_t)row*MSG + c];
    else if(c < GK){ int d = c-MSG; v = memory[(size_t)msg_nids[row]*D + d]; hprevf[row*D+d] = v; }
    else v = 0.f;
    ab[i] = f2b(v);
}
// fused split-K reduce + gates: upd = (1-u)*tanh(inn + r*hn) + u*h
__global__ void k_gates3(const float* part, const float* bias, const float* hprevf, float* upd){
    int i = blockIdx.x*256 + threadIdx.x;
    if(i >= MC*D) return;
    int row = i>>7, d = i&127;
    const float* p = part + (size_t)row*GN;
    const size_t S = (size_t)MC*GN;
    float gr = p[d]     + p[S+d]     + p[2*S+d]     + bias[d];
    float gu = p[128+d] + p[S+128+d] + p[2*S+128+d] + bias[128+d];
    float gi = p[256+d] + p[S+256+d] + p[2*S+256+d] + bias[256+d];
    float gh = p[384+d] + p[S+384+d] + p[2*S+384+d] + bias[384+d];
    float r = sigmoidf_(gr);
    float u = sigmoidf_(gu);
    float n = tanhf(gi + r*gh);
    upd[i] = (1.f-u)*n + u*hprevf[i];
}

// ---------- node-update map ----------
__global__ void k_map_init(int* map){ int i = blockIdx.x*256+threadIdx.x; if(i<NNC) map[i] = -1; }
__global__ void k_map_scatter(const int* msg_nids, int* map){
    int i = blockIdx.x*256+threadIdx.x; if(i<MC) map[msg_nids[i]] = i;
}

// fused gather for both hops
__global__ void k_gatherf(const int* seed1,const int* seed0,const int* map,
                          const float* memory,const float* upd,
                          unsigned short* hb1, unsigned short* acat1,
                          unsigned short* hb0, unsigned short* acat0){
    int i = blockIdx.x*256 + threadIdx.x;
    const int total1 = N1C*D;
    int li; const int* seed; unsigned short* hb; unsigned short* acat; int ldav, hoff;
    if(i < total1){ li=i; seed=seed1; hb=hb1; acat=acat1; ldav=584; hoff=456; }
    else { li = i - total1; if(li >= N0C*D) return; seed=seed0; hb=hb0; acat=acat0; ldav=840; hoff=712; }
    int row = li>>7, c = li&127;
    int sid = seed[row];
    int mi = map[sid];
    float v = (mi>=0) ? upd[(size_t)mi*D + c] : memory[(size_t)sid*D + c];
    unsigned short u = f2b(v);
    hb[li] = u;
    acat[(size_t)row*ldav + hoff + c] = u;
}

// ---------- bf16 MFMA GEMM, reg-prefetch pipelined, optional split-K ----------
// SPLITK>1: writes f32 partials [z][M][ldc], no bias/relu
template<int BM, int SPLITK, bool RELU, bool OUTF32>
__global__ __launch_bounds__(256) void k_gmm(const unsigned short* A, int lda,
                                             const unsigned short* B, int ldb,
                                             const float* bias, void* Cp, int ldc,
                                             int K, int N, int M){
    constexpr int ASTR = 72;
    constexpr int BSTR = 72;
    constexpr int RPW = BM/4;
    constexpr int RT  = RPW/16;
    constexpr int AIT = BM/32;
    __shared__ unsigned short As[BM*ASTR];
    __shared__ unsigned short Bs[64*BSTR];
    int t = threadIdx.x;
    int wave = t>>6, lane = t&63;
    int l15 = lane&15, l4 = lane>>4;
    int m0 = blockIdx.y*BM, n0 = blockIdx.x*64;
    int ntiles = (K+63)>>6;
    int tbeg, tend;
    if(SPLITK==1){ tbeg=0; tend=ntiles; }
    else {
        int tper = (ntiles + SPLITK-1)/SPLITK;
        tbeg = blockIdx.z*tper;
        tend = min(ntiles, tbeg+tper);
    }
    f32x4 acc[RT][4];
    #pragma unroll
    for(int rt=0;rt<RT;++rt)
        #pragma unroll
        for(int ct=0;ct<4;++ct) acc[rt][ct] = (f32x4){0.f,0.f,0.f,0.f};

    uint4 apre[AIT]; unsigned short bpre[16];
    auto loadA = [&](int kt){
        int k0 = kt<<6;
        #pragma unroll
        for(int i=0;i<AIT;++i){
            int idx = t + i*256;
            int row = idx>>3; int kc = (idx&7)*8;
            uint4 v = {0u,0u,0u,0u};
            if(k0+kc < K) v = *(const uint4*)(A + (size_t)(m0+row)*lda + k0 + kc);
            apre[i] = v;
        }
    };
    auto loadB = [&](int kt){
        int k0 = kt<<6;
        int n = t&63; int kb = (t>>6)*16;
        int ng = n0+n;
        #pragma unroll
        for(int j=0;j<16;++j){
            int kg = k0 + kb + j;
            bpre[j] = (kg<K && ng<N) ? B[(size_t)kg*ldb + ng] : (unsigned short)0;
        }
    };
    auto stash = [&](){
        #pragma unroll
        for(int i=0;i<AIT;++i){
            int idx = t + i*256;
            int row = idx>>3; int kc = (idx&7)*8;
            *(uint4*)&As[row*ASTR + kc] = apre[i];
        }
        int n = t&63; int kb = (t>>6)*16;
        #pragma unroll
        for(int j=0;j<16;++j) Bs[n*BSTR + kb + j] = bpre[j];
    };

    loadA(tbeg); loadB(tbeg);
    for(int kt=tbeg; kt<tend; ++kt){
        stash();
        __syncthreads();
        if(kt+1 < tend){ loadA(kt+1); loadB(kt+1); }
        #pragma unroll
        for(int kk=0; kk<64; kk+=32){
            short8v bfr[4];
            #pragma unroll
            for(int ct=0;ct<4;++ct)
                bfr[ct] = *(const short8v*)&Bs[(ct*16+l15)*BSTR + kk + l4*8];
            #pragma unroll
            for(int rt=0;rt<RT;++rt){
                short8v afr = *(const short8v*)&As[(wave*RPW + rt*16 + l15)*ASTR + kk + l4*8];
                #pragma unroll
                for(int ct=0;ct<4;++ct)
                    acc[rt][ct] = __builtin_amdgcn_mfma_f32_16x16x32_bf16(afr, bfr[ct], acc[rt][ct], 0,0,0);
            }
        }
        __syncthreads();
    }
    #pragma unroll
    for(int rt=0;rt<RT;++rt){
        #pragma unroll
        for(int ct=0;ct<4;++ct){
            int col = n0 + ct*16 + l15;
            if(col < N){
                #pragma unroll
                for(int r=0;r<4;++r){
                    int row = m0 + wave*RPW + rt*16 + l4*4 + r;
                    if(SPLITK==1){
                        float v = acc[rt][ct][r] + bias[col];
                        if(RELU) v = fmaxf(v, 0.f);
                        if(OUTF32) ((float*)Cp)[(size_t)row*ldc + col] = v;
                        else ((unsigned short*)Cp)[(size_t)row*ldc + col] = f2b(v);
                    } else {
                        ((float*)Cp)[((size_t)blockIdx.z*M + row)*ldc + col] = acc[rt][ct][r];
                    }
                }
            }
        }
    }
}

// split-K reduce + bias (+relu); N power of two
template<int SPL, bool RELU, bool OUTF32>
__global__ void k_kred(const float* part, int M, int N, const float* bias, void* out){
    int i = blockIdx.x*256 + threadIdx.x;
    if(i >= M*N) return;
    int col = i & (N-1);
    float v = bias[col];
    #pragma unroll
    for(int z=0;z<SPL;++z) v += part[(size_t)z*M*N + i];
    if(RELU) v = fmaxf(v, 0.f);
    if(OUTF32) ((float*)out)[i] = v;
    else ((unsigned short*)out)[i] = f2b(v);
}

// fused scores + masked softmax + av; quad-lane mapping; mask-skip (exact);
// NPW nodes per wave; time_w/time_b hoisted
template<int K, int CMIN, int S4, int NPW>
__global__ __launch_bounds__(256) void k_attn(const unsigned short* qwb,
    unsigned short* avout, int ldav,
    const float* times, const float* nbr_times, const float* nbr_feats,
    const int* nbr_mask, const int* nbr_local, const unsigned short* zbuf,
    const float* time_w, const float* time_b){
    constexpr int SPAN = KIN - CMIN;
    constexpr int QSTR = SPAN + 4;
    constexpr int QLD  = 2*QSTR;
    int wv = blockIdx.x*4 + (threadIdx.x>>6);
    int lane = threadIdx.x & 63;

    float4 tw4[S4], tb4[S4];
    #pragma unroll
    for(int s=0;s<S4;++s){
        int c = CMIN + s*256 + lane*4;
        if(c >= D+E && c < KIN){
            tw4[s] = *(const float4*)(time_w + (c-(D+E)));
            tb4[s] = *(const float4*)(time_b + (c-(D+E)));
        } else {
            tw4[s] = make_float4(0.f,0.f,0.f,0.f);
            tb4[s] = make_float4(0.f,0.f,0.f,0.f);
        }
    }

    for(int i=0;i<NPW;++i){
        int n = wv*NPW + i;
        const unsigned short* qrow = qwb + (size_t)n*QLD;
        float tval = (lane<K) ? nbr_times[(size_t)n*K + lane] : 0.f;
        int   mval = (lane<K) ? nbr_mask [(size_t)n*K + lane] : 0;
        int   nlv  = (CMIN==0 && lane<K) ? nbr_local[(size_t)n*K + lane] : 0;
        float tn = times[n];

        float4 qw4[NHD][S4]; float qb[NHD];
        #pragma unroll
        for(int h=0;h<NHD;++h){
            qb[h] = b2f(qrow[h*QSTR + SPAN]);
            #pragma unroll
            for(int s=0;s<S4;++s){
                int cl = s*256 + lane*4;
                float4 v = make_float4(0.f,0.f,0.f,0.f);
                if(cl < SPAN){
                    uint2 w = *(const uint2*)(qrow + h*QSTR + cl);
                    v.x = __uint_as_float(w.x<<16);
                    v.y = __uint_as_float(w.x & 0xffff0000u);
                    v.z = __uint_as_float(w.y<<16);
                    v.w = __uint_as_float(w.y & 0xffff0000u);
                }
                qw4[h][s] = v;
            }
        }

        float4 kin4[K][S4];
        float sval[NHD][K];
        unsigned int actmask = 0;
        #pragma unroll
        for(int k=0;k<K;++k){
            int mk = __shfl(mval, k);
            if(mk > 0){
                actmask |= (1u<<k);
                float dt = tn - __shfl(tval, k);
                const float* ef = nbr_feats + (size_t)(n*K+k)*E;
                const unsigned short* zf = (CMIN==0) ?
                    (zbuf + (size_t)(__shfl(nlv,k) - N0C)*D) : (const unsigned short*)0;
                float p0=0.f, p1=0.f;
                #pragma unroll
                for(int s=0;s<S4;++s){
                    int c = CMIN + s*256 + lane*4;
                    float4 kv = make_float4(0.f,0.f,0.f,0.f);
                    if(c < KIN){
                        if(CMIN==0 && c < D){
                            uint2 w = *(const uint2*)(zf + c);
                            kv.x = __uint_as_float(w.x<<16);
                            kv.y = __uint_as_float(w.x & 0xffff0000u);
                            kv.z = __uint_as_float(w.y<<16);
                            kv.w = __uint_as_float(w.y & 0xffff0000u);
                        } else if(c < D+E){
                            kv = *(const float4*)(ef + (c-D));
                        } else {
                            kv.x = __cosf(dt*tw4[s].x + tb4[s].x);
                            kv.y = __cosf(dt*tw4[s].y + tb4[s].y);
                            kv.z = __cosf(dt*tw4[s].z + tb4[s].z);
                            kv.w = __cosf(dt*tw4[s].w + tb4[s].w);
                        }
                    }
                    kin4[k][s] = kv;
                    p0 += kv.x*qw4[0][s].x + kv.y*qw4[0][s].y + kv.z*qw4[0][s].z + kv.w*qw4[0][s].w;
                    p1 += kv.x*qw4[1][s].x + kv.y*qw4[1][s].y + kv.z*qw4[1][s].z + kv.w*qw4[1][s].w;
                }
                #pragma unroll
                for(int off=32; off; off>>=1){ p0 += __shfl_xor(p0, off); p1 += __shfl_xor(p1, off); }
                sval[0][k] = (p0 + qb[0])*0.125f;
                sval[1][k] = (p1 + qb[1])*0.125f;
            } else {
                #pragma unroll
                for(int s=0;s<S4;++s) kin4[k][s] = make_float4(0.f,0.f,0.f,0.f);
                sval[0][k] = -1e9f;
                sval[1][k] = -1e9f;
            }
        }
        #pragma unroll
        for(int h=0;h<NHD;++h){
            float mx = -1e30f;
            #pragma unroll
            for(int k=0;k<K;++k) mx = fmaxf(mx, sval[h][k]);
            float z=0.f;
            #pragma unroll
            for(int k=0;k<K;++k){ float e = __expf(sval[h][k]-mx); sval[h][k]=e; z+=e; }
            float inv = 1.f/z;
            #pragma unroll
            for(int k=0;k<K;++k) sval[h][k]*=inv;
        }
        #pragma unroll
        for(int h=0;h<NHD;++h)
          #pragma unroll
          for(int s=0;s<S4;++s){
            int cl = s*256 + lane*4;
            if(cl < SPAN){
                float v0=0.f,v1=0.f,v2=0.f,v3=0.f;
                #pragma unroll
                for(int k=0;k<K;++k){
                    if(actmask & (1u<<k)){
                        float a = sval[h][k];
                        v0 += a*kin4[k][s].x; v1 += a*kin4[k][s].y;
                        v2 += a*kin4[k][s].z; v3 += a*kin4[k][s].w;
                    }
                }
                uint2 o;
                o.x = (unsigned int)f2b(v0) | ((unsigned int)f2b(v1)<<16);
                o.y = (unsigned int)f2b(v2) | ((unsigned int)f2b(v3)<<16);
                *(uint2*)(avout + (size_t)n*ldav + h*SPAN + cl) = o;
            }
          }
    }
}

// link prediction
__global__ __launch_bounds__(128) void k_linkpred(const float* z0,
      const int* src,const int* dst,const int* neg,
      const float* Ws,const float* bs,const float* Wd,const float* bd,
      const float* Wo,const float* bo, float* out){
    __shared__ float zs[D], zd[D], zn[D];
    __shared__ float red[4];
    int b = blockIdx.x; int d = threadIdx.x;
    zs[d] = z0[(size_t)src[b]*D + d];
    zd[d] = z0[(size_t)dst[b]*D + d];
    zn[d] = z0[(size_t)neg[b]*D + d];
    __syncthreads();
    float ss=0.f, sdd=0.f, snn=0.f;
    for(int c=0;c<D;++c){
        float w1 = Ws[c*D + d], w2 = Wd[c*D + d];
        ss  += zs[c]*w1; sdd += zd[c]*w2; snn += zn[c]*w2;
    }
    float bb = bs[d] + bd[d];
    float h1 = fmaxf(ss + sdd + bb, 0.f);
    float h2 = fmaxf(ss + snn + bb, 0.f);
    float w = Wo[d];
    float v1 = h1*w, v2 = h2*w;
    #pragma unroll
    for(int off=32; off; off>>=1){ v1 += __shfl_xor(v1,off); v2 += __shfl_xor(v2,off); }
    int wid = d>>6;
    if((d&63)==0){ red[wid*2]=v1; red[wid*2+1]=v2; }
    __syncthreads();
    if(d==0){
        out[b]       = sigmoidf_(red[0]+red[2] + bo[0]);
        out[BSZ + b] = sigmoidf_(red[1]+red[3] + bo[0]);
    }
}

extern "C" void kernel_launch(void* const* d_in, const int* in_sizes, int n_in,
                              void* d_out, int out_size, void* d_ws, size_t ws_size,
                              hipStream_t stream) {
    const float* memory  = (const float*)d_in[0];
    const float* time_w  = (const float*)d_in[1];
    const float* time_b  = (const float*)d_in[2];
    const float* gWih    = (const float*)d_in[3];
    const float* gbih    = (const float*)d_in[4];
    const float* gWhh    = (const float*)d_in[5];
    const float* gbhh    = (const float*)d_in[6];
    const float* Wq0=(const float*)d_in[7],  *bq0=(const float*)d_in[8];
    const float* Wk0=(const float*)d_in[9],  *bk0=(const float*)d_in[10];
    const float* Wv0=(const float*)d_in[11], *bv0=(const float*)d_in[12];
    const float* Wo0=(const float*)d_in[13], *bo0=(const float*)d_in[14];
    const float* Wq1=(const float*)d_in[15], *bq1=(const float*)d_in[16];
    const float* Wk1=(const float*)d_in[17], *bk1=(const float*)d_in[18];
    const float* Wv1=(const float*)d_in[19], *bv1=(const float*)d_in[20];
    const float* Wo1=(const float*)d_in[21], *bo1=(const float*)d_in[22];
    const float* lpWs=(const float*)d_in[23], *lpbs=(const float*)d_in[24];
    const float* lpWd=(const float*)d_in[25], *lpbd=(const float*)d_in[26];
    const float* lpWo=(const float*)d_in[27], *lpbo=(const float*)d_in[28];
    const float* msgs    = (const float*)d_in[29];
    const float* times0  = (const float*)d_in[30];
    const float* ntimes0 = (const float*)d_in[31];
    const float* nfeats0 = (const float*)d_in[32];
    const float* times1  = (const float*)d_in[33];
    const float* ntimes1 = (const float*)d_in[34];
    const float* nfeats1 = (const float*)d_in[35];
    const int* msg_nids  = (const int*)d_in[36];
    const int* seed0     = (const int*)d_in[37];
    const int* seed1     = (const int*)d_in[38];
    const int* nbr_local0= (const int*)d_in[39];
    const int* nbr_mask0 = (const int*)d_in[40];
    const int* nbr_mask1 = (const int*)d_in[41];
    const int* src       = (const int*)d_in[42];
    const int* dst       = (const int*)d_in[43];
    const int* neg       = (const int*)d_in[44];

    char* ws = (char*)d_ws;
    size_t off = 0;
    auto alloc = [&](size_t bytes)->char*{
        char* p = ws + off;
        off += (bytes + 255) & ~(size_t)255;
        return p;
    };
    int*   map   = (int*)  alloc((size_t)NNC*4);
    float* upd   = (float*)alloc((size_t)MC*D*4);
    unsigned short* hb1   = (unsigned short*)alloc((size_t)N1C*D*2);
    unsigned short* qwb1  = (unsigned short*)alloc((size_t)N1C*464*2);
    unsigned short* acat1 = (unsigned short*)alloc((size_t)N1C*584*2);
    unsigned short* zb1   = (unsigned short*)alloc((size_t)N1C*D*2);
    unsigned short* hb0   = (unsigned short*)alloc((size_t)N0C*D*2);
    unsigned short* qwb0  = (unsigned short*)alloc((size_t)N0C*720*2);
    unsigned short* acat0 = (unsigned short*)alloc((size_t)N0C*840*2);
    float* z0    = (float*)alloc((size_t)N0C*D*4);
    float* qc0   = (float*)alloc(512);
    float* qc1   = (float*)alloc(512);
    float* cb0   = (float*)alloc(512);
    float* cb1   = (float*)alloc(512);
    unsigned short* WFb0 = (unsigned short*)alloc((size_t)D*720*2);
    unsigned short* WFb1 = (unsigned short*)alloc((size_t)D*464*2);
    float* cF0   = (float*)alloc((size_t)720*4);
    float* cF1   = (float*)alloc((size_t)464*4);
    unsigned short* Bcat1 = (unsigned short*)alloc((size_t)584*D*2);
    unsigned short* Bcat0 = (unsigned short*)alloc((size_t)840*D*2);
    unsigned short* gA    = (unsigned short*)alloc((size_t)MC*GKP*2);
    unsigned short* gB    = (unsigned short*)alloc((size_t)GK*GN*2);
    float* gBias = (float*)alloc((size_t)GN*4);
    float* hprevf= (float*)alloc((size_t)MC*D*4);
    float* part  = (float*)alloc((size_t)2*N1C*D*4);   // 31.5 MB, shared by all split-K
    float* outp = (float*)d_out;

    // precompute
    k_pre_small<<<1,128,0,stream>>>(time_b, Wq0,bq0,Wq1,bq1, bv0,Wo0,bo0, bv1,Wo1,bo1,
                                    qc0,qc1,cb0,cb1);
    k_wf<<<720,128,0,stream>>>(Wq0,Wk0,bk0,qc0, WFb0,cF0, 0);
    k_wf<<<464,128,0,stream>>>(Wq1,Wk1,bk1,qc1, WFb1,cF1, 128);
    k_bcat<<<584,128,0,stream>>>(Wv1, Wo1, Bcat1, 128);
    k_bcat<<<840,128,0,stream>>>(Wv0, Wo0, Bcat0, 0);
    k_gruB<<<dim3(10,8),256,0,stream>>>(gWih, gWhh, gB);
    k_gruBias<<<2,256,0,stream>>>(gbih, gbhh, gBias);

    // GRU memory update via split-K MFMA GEMM + fused reduce/gates
    k_map_init<<<(NNC+255)/256,256,0,stream>>>(map);
    k_map_scatter<<<MC/256,256,0,stream>>>(msg_nids, map);
    k_acvt<<<(MC*GKP+255)/256,256,0,stream>>>(msgs, memory, msg_nids, gA, hprevf);
    k_gmm<128,3,false,true><<<dim3(GN/64, MC/128, 3),256,0,stream>>>(gA,GKP, gB,GN, gBias, part,GN, GK, GN, MC);
    k_gates3<<<(MC*D+255)/256,256,0,stream>>>(part, gBias, hprevf, upd);

    // gather node states (both hops) -> bf16
    k_gatherf<<<((N1C+N0C)*D)/256,256,0,stream>>>(seed1, seed0, map, memory, upd,
                                                  hb1, acat1, hb0, acat0);

    // GEMM1 (MFMA): qw = h @ WF + cF
    k_gmm<128,1,false,false><<<dim3(8,  N1C/128),256,0,stream>>>(hb1,128, WFb1,464, cF1, qwb1,464, 128, 464, N1C);
    k_gmm<128,1,false,false><<<dim3(12, N0C/128),256,0,stream>>>(hb0,128, WFb0,720, cF0, qwb0,720, 128, 720, N0C);

    // hop 1 attention (NPW=2 -> 3840 blocks)
    k_attn<K1C,128,1,2><<<N1C/8,256,0,stream>>>(qwb1, acat1, 584, times1, ntimes1, nfeats1,
                                                nbr_mask1, (const int*)0, (const unsigned short*)0,
                                                time_w, time_b);
    // GEMM2 hop1: split-K=2 (960 blocks) + reduce -> bf16 zb1
    k_gmm<128,2,true,false><<<dim3(2, N1C/128, 2),256,0,stream>>>(acat1,584, Bcat1,D, cb1, part,D, 584, D, N1C);
    k_kred<2,true,false><<<(N1C*D+255)/256,256,0,stream>>>(part, N1C, D, cb1, zb1);

    // hop 0 attention (NPW=1 -> 1536 blocks)
    k_attn<K0C,0,2,1><<<N0C/4,256,0,stream>>>(qwb0, acat0, 840, times0, ntimes0, nfeats0,
                                              nbr_mask0, nbr_local0, zb1,
                                              time_w, time_b);
    // GEMM2 hop0: BM=64, split-K=4 (768 blocks) + reduce -> f32 z0
    k_gmm<64,4,true,true><<<dim3(2, N0C/64, 4),256,0,stream>>>(acat0,840, Bcat0,D, cb0, part,D, 840, D, N0C);
    k_kred<4,true,true><<<(N0C*D+255)/256,256,0,stream>>>(part, N0C, D, cb0, z0);

    // link prediction
    k_linkpred<<<BSZ,128,0,stream>>>(z0, src,dst,neg, lpWs,lpbs,lpWd,lpbd, lpWo,lpbo, outp);
}